// Round 1
// baseline (1064.900 us; speedup 1.0000x reference)
//
#include <hip/hip_runtime.h>

#define NN 50000
#define NE 800000
#define INDIM 256
#define HIDD 128
#define ODIM 3
#define EDIM 4
#define NLAYERS 4

// ---------------------------------------------------------------------------
// GEMM: C[M,N] = A[M,K] @ B[K,N] (+ bias), fp32, row-major.
// 64x64 tile, 256 threads, 4x4 micro-tile per thread, K-step 16.
// ---------------------------------------------------------------------------
__global__ __launch_bounds__(256) void gemm_bias(
    const float* __restrict__ A, const float* __restrict__ B,
    const float* __restrict__ bias, float* __restrict__ C,
    int M, int N, int K)
{
    __shared__ float As[16][68];   // [k][m], stride 68 floats (16B aligned rows)
    __shared__ float Bs[16][68];   // [k][n]

    const int tid  = threadIdx.x;
    const int tx   = tid & 15;     // N direction (4 cols each)
    const int ty   = tid >> 4;     // M direction (4 rows each)
    const int col0 = blockIdx.x * 64;
    const int row0 = blockIdx.y * 64;

    const int aIdx = tid * 4;
    const int am = aIdx >> 4;      // 0..63 tile row
    const int ak = aIdx & 15;      // 0,4,8,12
    const int bk = aIdx >> 6;      // 0..15
    const int bn = aIdx & 63;      // 0..60 step 4

    float acc[4][4] = {};

    for (int k0 = 0; k0 < K; k0 += 16) {
        int gm = row0 + am;
        float4 av = make_float4(0.f, 0.f, 0.f, 0.f);
        if (gm < M) av = *(const float4*)&A[(size_t)gm * K + k0 + ak];
        As[ak + 0][am] = av.x; As[ak + 1][am] = av.y;
        As[ak + 2][am] = av.z; As[ak + 3][am] = av.w;

        float4 bv = *(const float4*)&B[(size_t)(k0 + bk) * N + col0 + bn];
        *(float4*)&Bs[bk][bn] = bv;
        __syncthreads();

#pragma unroll
        for (int kk = 0; kk < 16; kk++) {
            float a0 = As[kk][ty * 4 + 0], a1 = As[kk][ty * 4 + 1];
            float a2 = As[kk][ty * 4 + 2], a3 = As[kk][ty * 4 + 3];
            float b0 = Bs[kk][tx * 4 + 0], b1 = Bs[kk][tx * 4 + 1];
            float b2 = Bs[kk][tx * 4 + 2], b3 = Bs[kk][tx * 4 + 3];
            acc[0][0] += a0 * b0; acc[0][1] += a0 * b1; acc[0][2] += a0 * b2; acc[0][3] += a0 * b3;
            acc[1][0] += a1 * b0; acc[1][1] += a1 * b1; acc[1][2] += a1 * b2; acc[1][3] += a1 * b3;
            acc[2][0] += a2 * b0; acc[2][1] += a2 * b1; acc[2][2] += a2 * b2; acc[2][3] += a2 * b3;
            acc[3][0] += a3 * b0; acc[3][1] += a3 * b1; acc[3][2] += a3 * b2; acc[3][3] += a3 * b3;
        }
        __syncthreads();
    }

    float4 bb = make_float4(0.f, 0.f, 0.f, 0.f);
    if (bias) bb = *(const float4*)&bias[col0 + tx * 4];
#pragma unroll
    for (int i = 0; i < 4; i++) {
        int gm = row0 + ty * 4 + i;
        if (gm < M) {
            float4 o;
            o.x = acc[i][0] + bb.x; o.y = acc[i][1] + bb.y;
            o.z = acc[i][2] + bb.z; o.w = acc[i][3] + bb.w;
            *(float4*)&C[(size_t)gm * N + col0 + tx * 4] = o;
        }
    }
}

// ---------------------------------------------------------------------------
// CSR build: zero, histogram, 3-step exclusive scan, atomic-rank fill
// ---------------------------------------------------------------------------
__global__ void zero2_kernel(int* __restrict__ a, int* __restrict__ b) {
    int n = blockIdx.x * 256 + threadIdx.x;
    if (n < NN) { a[n] = 0; b[n] = 0; }
}

__global__ void hist_kernel(const int* __restrict__ dst, int* __restrict__ deg) {
    int e = blockIdx.x * 256 + threadIdx.x;
    if (e < NE) atomicAdd(&deg[dst[e]], 1);
}

__global__ void scan1_kernel(const int* __restrict__ deg, int* __restrict__ csr,
                             int* __restrict__ bsum) {
    __shared__ int s[256];
    int t = threadIdx.x;
    int n = blockIdx.x * 256 + t;
    int v = (n < NN) ? deg[n] : 0;
    s[t] = v; __syncthreads();
    for (int d = 1; d < 256; d <<= 1) {
        int u = (t >= d) ? s[t - d] : 0;
        __syncthreads();
        s[t] += u;
        __syncthreads();
    }
    if (n < NN) csr[n] = s[t] - v;          // local exclusive
    if (t == 255) bsum[blockIdx.x] = s[t];  // block total
}

__global__ void scan2_kernel(const int* __restrict__ bsum, int* __restrict__ boff) {
    __shared__ int s[256];
    int t = threadIdx.x;
    int v = (t < 196) ? bsum[t] : 0;
    s[t] = v; __syncthreads();
    for (int d = 1; d < 256; d <<= 1) {
        int u = (t >= d) ? s[t - d] : 0;
        __syncthreads();
        s[t] += u;
        __syncthreads();
    }
    boff[t] = s[t] - v;
}

__global__ void scan3_kernel(int* __restrict__ csr, const int* __restrict__ boff) {
    int n = blockIdx.x * 256 + threadIdx.x;
    if (n < NN) csr[n] += boff[blockIdx.x];
    if (n == 0) csr[NN] = NE;
}

__global__ void fill_kernel(const int* __restrict__ dst, const int* __restrict__ csr,
                            int* __restrict__ cursor, int* __restrict__ eid) {
    int e = blockIdx.x * 256 + threadIdx.x;
    if (e < NE) {
        int d = dst[e];
        int p = csr[d] + atomicAdd(&cursor[d], 1);
        eid[p] = e;
    }
}

// ---------------------------------------------------------------------------
// Aggregation: one wave per dst node, lane holds 2 channels.
// x[n] += sum_{e in-edges(n)} relu( z[src_e] + y[n] + ea_e @ W3 )   (in place)
// ---------------------------------------------------------------------------
__global__ __launch_bounds__(256) void agg_kernel(
    float* __restrict__ x, const float* __restrict__ z, const float* __restrict__ y,
    const float* __restrict__ ea, const float* __restrict__ W3,
    const int* __restrict__ eid, const int* __restrict__ csr,
    const int* __restrict__ src)
{
    int wid  = (blockIdx.x * 256 + threadIdx.x) >> 6;
    int lane = threadIdx.x & 63;
    if (wid >= NN) return;
    int c0 = lane * 2;

    float w00 = W3[0 * HIDD + c0],     w01 = W3[1 * HIDD + c0];
    float w02 = W3[2 * HIDD + c0],     w03 = W3[3 * HIDD + c0];
    float w10 = W3[0 * HIDD + c0 + 1], w11 = W3[1 * HIDD + c0 + 1];
    float w12 = W3[2 * HIDD + c0 + 1], w13 = W3[3 * HIDD + c0 + 1];

    float2 yv  = *(const float2*)&y[(size_t)wid * HIDD + c0];
    float2 acc = *(const float2*)&x[(size_t)wid * HIDD + c0];

    int i = csr[wid], end = csr[wid + 1];
    for (; i < end; i++) {
        int e = eid[i];
        int s = src[e];
        float2 zv = *(const float2*)&z[(size_t)s * HIDD + c0];
        float4 a  = *(const float4*)&ea[(size_t)e * EDIM];
        float m0 = zv.x + yv.x + a.x * w00 + a.y * w01 + a.z * w02 + a.w * w03;
        float m1 = zv.y + yv.y + a.x * w10 + a.y * w11 + a.z * w12 + a.w * w13;
        acc.x += fmaxf(m0, 0.f);
        acc.y += fmaxf(m1, 0.f);
    }
    *(float2*)&x[(size_t)wid * HIDD + c0] = acc;
}

// ---------------------------------------------------------------------------
// Output projection: out[n] = x[n] @ W_out + b_out   ([50000,128]@[128,3])
// ---------------------------------------------------------------------------
__global__ __launch_bounds__(256) void out_kernel(
    const float* __restrict__ x, const float* __restrict__ Wo,
    const float* __restrict__ bo, float* __restrict__ out)
{
    int wid  = (blockIdx.x * 256 + threadIdx.x) >> 6;
    int lane = threadIdx.x & 63;
    if (wid >= NN) return;
    float2 xv = *(const float2*)&x[(size_t)wid * HIDD + lane * 2];
#pragma unroll
    for (int c = 0; c < ODIM; c++) {
        float p = xv.x * Wo[(lane * 2) * ODIM + c] + xv.y * Wo[(lane * 2 + 1) * ODIM + c];
#pragma unroll
        for (int off = 32; off; off >>= 1) p += __shfl_xor(p, off);
        if (lane == 0) out[(size_t)wid * ODIM + c] = p + bo[c];
    }
}

// ---------------------------------------------------------------------------
extern "C" void kernel_launch(void* const* d_in, const int* in_sizes, int n_in,
                              void* d_out, int out_size, void* d_ws, size_t ws_size,
                              hipStream_t stream)
{
    const float* h     = (const float*)d_in[0];
    const int*   ei    = (const int*)  d_in[1];
    const float* ea    = (const float*)d_in[2];
    const float* W_in  = (const float*)d_in[3];
    const float* b_in  = (const float*)d_in[4];
    const float* W_msg = (const float*)d_in[5];
    const float* b_msg = (const float*)d_in[6];
    const float* W_out = (const float*)d_in[7];
    const float* b_out = (const float*)d_in[8];
    float* out = (float*)d_out;

    // workspace carve-up (~81 MB)
    float* x      = (float*)d_ws;
    float* z      = x + (size_t)NN * HIDD;
    float* y      = z + (size_t)NN * HIDD;
    int*   deg    = (int*)(y + (size_t)NN * HIDD);
    int*   cursor = deg + 50176;
    int*   csr    = cursor + 50176;    // NN+1 used
    int*   eidArr = csr + 50176;
    int*   bsum   = eidArr + NE;
    int*   boff   = bsum + 256;

    const int* srcA = ei;        // edge_index[0]
    const int* dstA = ei + NE;   // edge_index[1]

    // CSR build (once per call; reused by all 4 layers)
    zero2_kernel<<<196, 256, 0, stream>>>(deg, cursor);
    hist_kernel <<<3125, 256, 0, stream>>>(dstA, deg);
    scan1_kernel<<<196, 256, 0, stream>>>(deg, csr, bsum);
    scan2_kernel<<<1, 256, 0, stream>>>(bsum, boff);
    scan3_kernel<<<196, 256, 0, stream>>>(csr, boff);
    fill_kernel <<<3125, 256, 0, stream>>>(dstA, csr, cursor, eidArr);

    // input projection: x = h @ W_in + b_in
    gemm_bias<<<dim3(2, 782), 256, 0, stream>>>(h, W_in, b_in, x, NN, HIDD, INDIM);

    for (int l = 0; l < NLAYERS; l++) {
        const float* Wl = W_msg + (size_t)l * (2 * HIDD + EDIM) * HIDD;
        // z = x @ W1 ; y = x @ W2 + b_msg[l]
        gemm_bias<<<dim3(2, 782), 256, 0, stream>>>(x, Wl, nullptr, z, NN, HIDD, HIDD);
        gemm_bias<<<dim3(2, 782), 256, 0, stream>>>(x, Wl + 128 * HIDD, b_msg + l * HIDD, y, NN, HIDD, HIDD);
        // x[n] += sum relu(z[src] + y[n] + ea@W3)
        agg_kernel<<<12500, 256, 0, stream>>>(x, z, y, ea, Wl + 256 * HIDD, eidArr, csr, srcA);
    }

    out_kernel<<<12500, 256, 0, stream>>>(x, W_out, b_out, out);
}

// Round 2
// 877.953 us; speedup vs baseline: 1.2129x; 1.2129x over previous
//
#include <hip/hip_runtime.h>

#define NN 50000
#define NE 800000
#define INDIM 256
#define HIDD 128
#define ODIM 3
#define EDIM 4
#define NLAYERS 4

// ---------------------------------------------------------------------------
// GEMM: C[M,N] = A[M,K] @ B[K,N] (+ bias), fp32, row-major.
// 64x64 tile, 256 threads, 4x4 micro-tile per thread, K-step 16.
// ---------------------------------------------------------------------------
__global__ __launch_bounds__(256) void gemm_bias(
    const float* __restrict__ A, const float* __restrict__ B,
    const float* __restrict__ bias, float* __restrict__ C,
    int M, int N, int K)
{
    __shared__ float As[16][68];   // [k][m]
    __shared__ float Bs[16][68];   // [k][n]

    const int tid  = threadIdx.x;
    const int tx   = tid & 15;     // N direction (4 cols each)
    const int ty   = tid >> 4;     // M direction (4 rows each)
    const int col0 = blockIdx.x * 64;
    const int row0 = blockIdx.y * 64;

    const int aIdx = tid * 4;
    const int am = aIdx >> 4;
    const int ak = aIdx & 15;
    const int bk = aIdx >> 6;
    const int bn = aIdx & 63;

    float acc[4][4] = {};

    for (int k0 = 0; k0 < K; k0 += 16) {
        int gm = row0 + am;
        float4 av = make_float4(0.f, 0.f, 0.f, 0.f);
        if (gm < M) av = *(const float4*)&A[(size_t)gm * K + k0 + ak];
        As[ak + 0][am] = av.x; As[ak + 1][am] = av.y;
        As[ak + 2][am] = av.z; As[ak + 3][am] = av.w;

        float4 bv = *(const float4*)&B[(size_t)(k0 + bk) * N + col0 + bn];
        *(float4*)&Bs[bk][bn] = bv;
        __syncthreads();

#pragma unroll
        for (int kk = 0; kk < 16; kk++) {
            float4 a = *(const float4*)&As[kk][ty * 4];
            float4 b = *(const float4*)&Bs[kk][tx * 4];
            acc[0][0] += a.x * b.x; acc[0][1] += a.x * b.y; acc[0][2] += a.x * b.z; acc[0][3] += a.x * b.w;
            acc[1][0] += a.y * b.x; acc[1][1] += a.y * b.y; acc[1][2] += a.y * b.z; acc[1][3] += a.y * b.w;
            acc[2][0] += a.z * b.x; acc[2][1] += a.z * b.y; acc[2][2] += a.z * b.z; acc[2][3] += a.z * b.w;
            acc[3][0] += a.w * b.x; acc[3][1] += a.w * b.y; acc[3][2] += a.w * b.z; acc[3][3] += a.w * b.w;
        }
        __syncthreads();
    }

    float4 bb = make_float4(0.f, 0.f, 0.f, 0.f);
    if (bias) bb = *(const float4*)&bias[col0 + tx * 4];
#pragma unroll
    for (int i = 0; i < 4; i++) {
        int gm = row0 + ty * 4 + i;
        if (gm < M) {
            float4 o;
            o.x = acc[i][0] + bb.x; o.y = acc[i][1] + bb.y;
            o.z = acc[i][2] + bb.z; o.w = acc[i][3] + bb.w;
            *(float4*)&C[(size_t)gm * N + col0 + tx * 4] = o;
        }
    }
}

// ---------------------------------------------------------------------------
// CSR build
// ---------------------------------------------------------------------------
__global__ void zero2_kernel(int* __restrict__ a, int* __restrict__ b) {
    int n = blockIdx.x * 256 + threadIdx.x;
    if (n < NN) { a[n] = 0; b[n] = 0; }
}

__global__ void hist_kernel(const int* __restrict__ dst, int* __restrict__ deg) {
    int e = blockIdx.x * 256 + threadIdx.x;
    if (e < NE) atomicAdd(&deg[dst[e]], 1);
}

__global__ void scan1_kernel(const int* __restrict__ deg, int* __restrict__ csr,
                             int* __restrict__ bsum) {
    __shared__ int s[256];
    int t = threadIdx.x;
    int n = blockIdx.x * 256 + t;
    int v = (n < NN) ? deg[n] : 0;
    s[t] = v; __syncthreads();
    for (int d = 1; d < 256; d <<= 1) {
        int u = (t >= d) ? s[t - d] : 0;
        __syncthreads();
        s[t] += u;
        __syncthreads();
    }
    if (n < NN) csr[n] = s[t] - v;
    if (t == 255) bsum[blockIdx.x] = s[t];
}

__global__ void scan2_kernel(const int* __restrict__ bsum, int* __restrict__ boff) {
    __shared__ int s[256];
    int t = threadIdx.x;
    int v = (t < 196) ? bsum[t] : 0;
    s[t] = v; __syncthreads();
    for (int d = 1; d < 256; d <<= 1) {
        int u = (t >= d) ? s[t - d] : 0;
        __syncthreads();
        s[t] += u;
        __syncthreads();
    }
    boff[t] = s[t] - v;
}

__global__ void scan3_kernel(int* __restrict__ csr, const int* __restrict__ boff) {
    int n = blockIdx.x * 256 + threadIdx.x;
    if (n < NN) csr[n] += boff[blockIdx.x];
    if (n == 0) csr[NN] = NE;
}

// fill: also pre-gather src into CSR order (srcS) so agg has only ONE
// random indirection (z[s]) instead of a 3-deep dependent chain.
__global__ void fill_kernel(const int* __restrict__ dst, const int* __restrict__ src,
                            const int* __restrict__ csr, int* __restrict__ cursor,
                            int* __restrict__ eid, int* __restrict__ srcS) {
    int e = blockIdx.x * 256 + threadIdx.x;
    if (e < NE) {
        int d = dst[e];
        int p = csr[d] + atomicAdd(&cursor[d], 1);
        eid[p] = e;
        srcS[p] = src[e];
    }
}

// ---------------------------------------------------------------------------
// Aggregation: one wave per dst node, lane holds 2 channels, 4-edge batches.
// x[n] += sum_{e in-edges(n)} relu( z[src_e] + y[n] + ea_e @ W3 )   (in place)
// ---------------------------------------------------------------------------
__global__ __launch_bounds__(256) void agg_kernel(
    float* __restrict__ x, const float* __restrict__ z, const float* __restrict__ y,
    const float* __restrict__ ea, const float* __restrict__ W3,
    const int* __restrict__ eid, const int* __restrict__ srcS,
    const int* __restrict__ csr)
{
    int wid  = (blockIdx.x * 256 + threadIdx.x) >> 6;
    int lane = threadIdx.x & 63;
    if (wid >= NN) return;
    int c0 = lane * 2;

    float w00 = W3[0 * HIDD + c0],     w01 = W3[1 * HIDD + c0];
    float w02 = W3[2 * HIDD + c0],     w03 = W3[3 * HIDD + c0];
    float w10 = W3[0 * HIDD + c0 + 1], w11 = W3[1 * HIDD + c0 + 1];
    float w12 = W3[2 * HIDD + c0 + 1], w13 = W3[3 * HIDD + c0 + 1];

    float2 yv  = *(const float2*)&y[(size_t)wid * HIDD + c0];
    float2 acc = *(const float2*)&x[(size_t)wid * HIDD + c0];

    int i = csr[wid], end = csr[wid + 1];

    // 4-wide batches: 4 independent z-gathers + 4 ea broadcasts in flight
    for (; i + 3 < end; i += 4) {
        int s0 = srcS[i], s1 = srcS[i + 1], s2 = srcS[i + 2], s3 = srcS[i + 3];
        int e0 = eid[i],  e1 = eid[i + 1],  e2 = eid[i + 2],  e3 = eid[i + 3];
        float2 z0 = *(const float2*)&z[(size_t)s0 * HIDD + c0];
        float2 z1 = *(const float2*)&z[(size_t)s1 * HIDD + c0];
        float2 z2 = *(const float2*)&z[(size_t)s2 * HIDD + c0];
        float2 z3 = *(const float2*)&z[(size_t)s3 * HIDD + c0];
        float4 a0 = *(const float4*)&ea[(size_t)e0 * EDIM];
        float4 a1 = *(const float4*)&ea[(size_t)e1 * EDIM];
        float4 a2 = *(const float4*)&ea[(size_t)e2 * EDIM];
        float4 a3 = *(const float4*)&ea[(size_t)e3 * EDIM];

        float m;
        m = z0.x + yv.x + a0.x * w00 + a0.y * w01 + a0.z * w02 + a0.w * w03; acc.x += fmaxf(m, 0.f);
        m = z0.y + yv.y + a0.x * w10 + a0.y * w11 + a0.z * w12 + a0.w * w13; acc.y += fmaxf(m, 0.f);
        m = z1.x + yv.x + a1.x * w00 + a1.y * w01 + a1.z * w02 + a1.w * w03; acc.x += fmaxf(m, 0.f);
        m = z1.y + yv.y + a1.x * w10 + a1.y * w11 + a1.z * w12 + a1.w * w13; acc.y += fmaxf(m, 0.f);
        m = z2.x + yv.x + a2.x * w00 + a2.y * w01 + a2.z * w02 + a2.w * w03; acc.x += fmaxf(m, 0.f);
        m = z2.y + yv.y + a2.x * w10 + a2.y * w11 + a2.z * w12 + a2.w * w13; acc.y += fmaxf(m, 0.f);
        m = z3.x + yv.x + a3.x * w00 + a3.y * w01 + a3.z * w02 + a3.w * w03; acc.x += fmaxf(m, 0.f);
        m = z3.y + yv.y + a3.x * w10 + a3.y * w11 + a3.z * w12 + a3.w * w13; acc.y += fmaxf(m, 0.f);
    }
    for (; i < end; i++) {
        int s = srcS[i];
        int e = eid[i];
        float2 zv = *(const float2*)&z[(size_t)s * HIDD + c0];
        float4 a  = *(const float4*)&ea[(size_t)e * EDIM];
        float m0 = zv.x + yv.x + a.x * w00 + a.y * w01 + a.z * w02 + a.w * w03;
        float m1 = zv.y + yv.y + a.x * w10 + a.y * w11 + a.z * w12 + a.w * w13;
        acc.x += fmaxf(m0, 0.f);
        acc.y += fmaxf(m1, 0.f);
    }
    *(float2*)&x[(size_t)wid * HIDD + c0] = acc;
}

// ---------------------------------------------------------------------------
// Output projection: out[n] = x[n] @ W_out + b_out   ([50000,128]@[128,3])
// ---------------------------------------------------------------------------
__global__ __launch_bounds__(256) void out_kernel(
    const float* __restrict__ x, const float* __restrict__ Wo,
    const float* __restrict__ bo, float* __restrict__ out)
{
    int wid  = (blockIdx.x * 256 + threadIdx.x) >> 6;
    int lane = threadIdx.x & 63;
    if (wid >= NN) return;
    float2 xv = *(const float2*)&x[(size_t)wid * HIDD + lane * 2];
#pragma unroll
    for (int c = 0; c < ODIM; c++) {
        float p = xv.x * Wo[(lane * 2) * ODIM + c] + xv.y * Wo[(lane * 2 + 1) * ODIM + c];
#pragma unroll
        for (int off = 32; off; off >>= 1) p += __shfl_xor(p, off);
        if (lane == 0) out[(size_t)wid * ODIM + c] = p + bo[c];
    }
}

// ---------------------------------------------------------------------------
extern "C" void kernel_launch(void* const* d_in, const int* in_sizes, int n_in,
                              void* d_out, int out_size, void* d_ws, size_t ws_size,
                              hipStream_t stream)
{
    const float* h     = (const float*)d_in[0];
    const int*   ei    = (const int*)  d_in[1];
    const float* ea    = (const float*)d_in[2];
    const float* W_in  = (const float*)d_in[3];
    const float* b_in  = (const float*)d_in[4];
    const float* W_msg = (const float*)d_in[5];
    const float* b_msg = (const float*)d_in[6];
    const float* W_out = (const float*)d_in[7];
    const float* b_out = (const float*)d_in[8];
    float* out = (float*)d_out;

    // workspace carve-up (~84 MB)
    float* x      = (float*)d_ws;
    float* z      = x + (size_t)NN * HIDD;
    float* y      = z + (size_t)NN * HIDD;
    int*   deg    = (int*)(y + (size_t)NN * HIDD);
    int*   cursor = deg + 50176;
    int*   csr    = cursor + 50176;    // NN+1 used
    int*   eidArr = csr + 50176;
    int*   srcS   = eidArr + NE;
    int*   bsum   = srcS + NE;
    int*   boff   = bsum + 256;

    const int* srcA = ei;        // edge_index[0]
    const int* dstA = ei + NE;   // edge_index[1]

    // CSR build (once per call; reused by all 4 layers)
    zero2_kernel<<<196, 256, 0, stream>>>(deg, cursor);
    hist_kernel <<<3125, 256, 0, stream>>>(dstA, deg);
    scan1_kernel<<<196, 256, 0, stream>>>(deg, csr, bsum);
    scan2_kernel<<<1, 256, 0, stream>>>(bsum, boff);
    scan3_kernel<<<196, 256, 0, stream>>>(csr, boff);
    fill_kernel <<<3125, 256, 0, stream>>>(dstA, srcA, csr, cursor, eidArr, srcS);

    // input projection: x = h @ W_in + b_in
    gemm_bias<<<dim3(2, 782), 256, 0, stream>>>(h, W_in, b_in, x, NN, HIDD, INDIM);

    for (int l = 0; l < NLAYERS; l++) {
        const float* Wl = W_msg + (size_t)l * (2 * HIDD + EDIM) * HIDD;
        gemm_bias<<<dim3(2, 782), 256, 0, stream>>>(x, Wl, nullptr, z, NN, HIDD, HIDD);
        gemm_bias<<<dim3(2, 782), 256, 0, stream>>>(x, Wl + 128 * HIDD, b_msg + l * HIDD, y, NN, HIDD, HIDD);
        agg_kernel<<<12500, 256, 0, stream>>>(x, z, y, ea, Wl + 256 * HIDD, eidArr, srcS, csr);
    }

    out_kernel<<<12500, 256, 0, stream>>>(x, W_out, b_out, out);
}

// Round 3
// 689.489 us; speedup vs baseline: 1.5445x; 1.2733x over previous
//
#include <hip/hip_runtime.h>

#define NN 50000
#define NE 800000
#define INDIM 256
#define HIDD 128
#define ODIM 3
#define EDIM 4
#define NLAYERS 4

typedef __attribute__((ext_vector_type(8))) short bf16x8;
typedef __attribute__((ext_vector_type(4))) float f32x4;

// round-to-nearest-even fp32 -> bf16 bits (finite inputs)
__device__ __forceinline__ ushort f2bf(float f) {
    unsigned int x = __float_as_uint(f);
    unsigned int r = (x + 0x7fffu + ((x >> 16) & 1u)) >> 16;
    return (ushort)r;
}
__device__ __forceinline__ float bf2f(ushort u) {
    return __uint_as_float(((unsigned int)u) << 16);
}

// ---------------------------------------------------------------------------
// MFMA GEMM, 128x128 tile, 256 threads (4 waves, each 64x64 = 4x4 MFMA tiles).
// C = (Ah [+Al]) @ (Bh [+Bl])^T-layout + bias, exact-split bf16 products:
//   Ah@Bh [+ Ah@Bl if useBl] [+ Al@Bh if useAl]
// B given PRE-TRANSPOSED as BT[n][k] (ldb = K stride).
// Output modes: Cb!=null -> bf16 C; else fp32 C (+= if beta1), and if Eh!=null
// also emit hi/lo bf16 split of C (for the next layer's A operand).
// ---------------------------------------------------------------------------
__global__ __launch_bounds__(256) void gemm_mfma(
    const ushort* __restrict__ Ah, const ushort* __restrict__ Al,
    const ushort* __restrict__ BTh, const ushort* __restrict__ BTl,
    const float* __restrict__ bias,
    float* __restrict__ Cf, ushort* __restrict__ Cb,
    ushort* __restrict__ Eh, ushort* __restrict__ El,
    int M, int K, int lda, int ldb, int ldc,
    int useAl, int useBl, int beta1)
{
    // row stride 40 shorts (80 B = 20 banks): 16 frag-rows land 2-way max (free)
    __shared__ __align__(16) ushort AsH[128 * 40];
    __shared__ __align__(16) ushort AsL[128 * 40];
    __shared__ __align__(16) ushort BsH[128 * 40];
    __shared__ __align__(16) ushort BsL[128 * 40];

    const int tid  = threadIdx.x;
    const int col0 = blockIdx.x * 128;
    const int row0 = blockIdx.y * 128;
    const int lane = tid & 63;
    const int wv   = tid >> 6;
    const int wr   = wv >> 1, wc = wv & 1;
    const int lm   = lane & 15, quad = lane >> 4;

    f32x4 acc[4][4];
#pragma unroll
    for (int i = 0; i < 4; i++)
#pragma unroll
        for (int j = 0; j < 4; j++)
#pragma unroll
            for (int t = 0; t < 4; t++) acc[i][j][t] = 0.f;

    for (int k0 = 0; k0 < K; k0 += 32) {
        __syncthreads();
        // stage 128x32 bf16 tiles: 512 16B-chunks per buffer, 2 per thread
#pragma unroll
        for (int c = 0; c < 2; c++) {
            int cid = tid + c * 256;
            int rr = cid >> 2, q = cid & 3;
            int koff = k0 + q * 8;
            int lofs = rr * 40 + q * 8;
            int4 z4 = make_int4(0, 0, 0, 0);
            int gr = row0 + rr;
            int4 va = z4;
            if (gr < M) va = *(const int4*)&Ah[(size_t)gr * lda + koff];
            *(int4*)&AsH[lofs] = va;
            if (useAl) {
                int4 vl = z4;
                if (gr < M) vl = *(const int4*)&Al[(size_t)gr * lda + koff];
                *(int4*)&AsL[lofs] = vl;
            }
            int gn = col0 + rr;
            *(int4*)&BsH[lofs] = *(const int4*)&BTh[(size_t)gn * ldb + koff];
            if (useBl)
                *(int4*)&BsL[lofs] = *(const int4*)&BTl[(size_t)gn * ldb + koff];
        }
        __syncthreads();

        bf16x8 ah[4], bh[4], al[4], bl[4];
#pragma unroll
        for (int i = 0; i < 4; i++) {
            int ao = (wr * 64 + i * 16 + lm) * 40 + quad * 8;
            int bo = (wc * 64 + i * 16 + lm) * 40 + quad * 8;
            ah[i] = *(bf16x8*)&AsH[ao];
            bh[i] = *(bf16x8*)&BsH[bo];
            if (useAl) al[i] = *(bf16x8*)&AsL[ao];
            if (useBl) bl[i] = *(bf16x8*)&BsL[bo];
        }
#pragma unroll
        for (int i = 0; i < 4; i++)
#pragma unroll
            for (int j = 0; j < 4; j++)
                acc[i][j] = __builtin_amdgcn_mfma_f32_16x16x32_bf16(ah[i], bh[j], acc[i][j], 0, 0, 0);
        if (useBl) {
#pragma unroll
            for (int i = 0; i < 4; i++)
#pragma unroll
                for (int j = 0; j < 4; j++)
                    acc[i][j] = __builtin_amdgcn_mfma_f32_16x16x32_bf16(ah[i], bl[j], acc[i][j], 0, 0, 0);
        }
        if (useAl) {
#pragma unroll
            for (int i = 0; i < 4; i++)
#pragma unroll
                for (int j = 0; j < 4; j++)
                    acc[i][j] = __builtin_amdgcn_mfma_f32_16x16x32_bf16(al[i], bh[j], acc[i][j], 0, 0, 0);
        }
    }

    float bj[4];
#pragma unroll
    for (int j = 0; j < 4; j++) {
        int gc = col0 + wc * 64 + j * 16 + lm;
        bj[j] = bias ? bias[gc] : 0.f;
    }
    // C/D layout: col = lane&15, row = quad*4 + reg
#pragma unroll
    for (int i = 0; i < 4; i++) {
#pragma unroll
        for (int t = 0; t < 4; t++) {
            int gr = row0 + wr * 64 + i * 16 + quad * 4 + t;
            if (gr < M) {
#pragma unroll
                for (int j = 0; j < 4; j++) {
                    int gc = col0 + wc * 64 + j * 16 + lm;
                    float v = acc[i][j][t] + bj[j];
                    size_t ci = (size_t)gr * ldc + gc;
                    if (Cb) {
                        Cb[ci] = f2bf(v);
                    } else {
                        if (beta1) v += Cf[ci];
                        Cf[ci] = v;
                        if (Eh) {
                            ushort hi = f2bf(v);
                            size_t xi = (size_t)gr * HIDD + gc;
                            Eh[xi] = hi;
                            El[xi] = f2bf(v - bf2f(hi));
                        }
                    }
                }
            }
        }
    }
}

// ---------------------------------------------------------------------------
// conversion / prep kernels
// ---------------------------------------------------------------------------
__global__ void conv_h_hi(const float* __restrict__ h, ushort* __restrict__ d) {
    int id = blockIdx.x * 256 + threadIdx.x;            // 3.2M, x4 elems
    float4 v = *(const float4*)&h[(size_t)id * 4];
    ushort4 o;
    o.x = f2bf(v.x); o.y = f2bf(v.y); o.z = f2bf(v.z); o.w = f2bf(v.w);
    *(ushort4*)&d[(size_t)id * 4] = o;
}

__global__ void conv_h_lo(const float* __restrict__ h, ushort* __restrict__ d) {
    int id = blockIdx.x * 256 + threadIdx.x;
    float4 v = *(const float4*)&h[(size_t)id * 4];
    ushort4 o;
    o.x = f2bf(v.x - bf2f(f2bf(v.x)));
    o.y = f2bf(v.y - bf2f(f2bf(v.y)));
    o.z = f2bf(v.z - bf2f(f2bf(v.z)));
    o.w = f2bf(v.w - bf2f(f2bf(v.w)));
    *(ushort4*)&d[(size_t)id * 4] = o;
}

__global__ void conv_win(const float* __restrict__ W, ushort* __restrict__ Th,
                         ushort* __restrict__ Tl) {
    int id = blockIdx.x * 256 + threadIdx.x;            // 32768
    int k = id >> 7, n = id & 127;
    float v = W[id];
    ushort hi = f2bf(v);
    Th[n * 256 + k] = hi;
    Tl[n * 256 + k] = f2bf(v - bf2f(hi));
}

// build B^T [n][k] for fused [W1|W2] (N=256,K=128) per layer + bias256
__global__ void conv_wzy(const float* __restrict__ Wm, const float* __restrict__ bm,
                         ushort* __restrict__ Th, ushort* __restrict__ Tl,
                         float* __restrict__ b256) {
    int id = blockIdx.x * 256 + threadIdx.x;            // 131072
    int l = id >> 15;
    int r = id & 32767;
    int n = r >> 7, k = r & 127;
    float v = (n < 128) ? Wm[l * 33280 + k * 128 + n]
                        : Wm[l * 33280 + (128 + k) * 128 + (n - 128)];
    ushort hi = f2bf(v);
    size_t o = (size_t)l * 32768 + (size_t)n * 128 + k;
    Th[o] = hi;
    Tl[o] = f2bf(v - bf2f(hi));
    if (k == 0) b256[l * 256 + n] = (n < 128) ? 0.f : bm[l * 128 + (n - 128)];
}

// ---------------------------------------------------------------------------
// CSR build
// ---------------------------------------------------------------------------
__global__ void zero2_kernel(int* __restrict__ a, int* __restrict__ b) {
    int n = blockIdx.x * 256 + threadIdx.x;
    if (n < NN) { a[n] = 0; b[n] = 0; }
}

__global__ void hist_kernel(const int* __restrict__ dst, int* __restrict__ deg) {
    int e = blockIdx.x * 256 + threadIdx.x;
    if (e < NE) atomicAdd(&deg[dst[e]], 1);
}

__global__ void scan1_kernel(const int* __restrict__ deg, int* __restrict__ csr,
                             int* __restrict__ bsum) {
    __shared__ int s[256];
    int t = threadIdx.x;
    int n = blockIdx.x * 256 + t;
    int v = (n < NN) ? deg[n] : 0;
    s[t] = v; __syncthreads();
    for (int d = 1; d < 256; d <<= 1) {
        int u = (t >= d) ? s[t - d] : 0;
        __syncthreads();
        s[t] += u;
        __syncthreads();
    }
    if (n < NN) csr[n] = s[t] - v;
    if (t == 255) bsum[blockIdx.x] = s[t];
}

__global__ void scan2_kernel(const int* __restrict__ bsum, int* __restrict__ boff) {
    __shared__ int s[256];
    int t = threadIdx.x;
    int v = (t < 196) ? bsum[t] : 0;
    s[t] = v; __syncthreads();
    for (int d = 1; d < 256; d <<= 1) {
        int u = (t >= d) ? s[t - d] : 0;
        __syncthreads();
        s[t] += u;
        __syncthreads();
    }
    boff[t] = s[t] - v;
}

__global__ void scan3_kernel(int* __restrict__ csr, const int* __restrict__ boff) {
    int n = blockIdx.x * 256 + threadIdx.x;
    if (n < NN) csr[n] += boff[blockIdx.x];
    if (n == 0) csr[NN] = NE;
}

__global__ void fill_kernel(const int* __restrict__ dst, const int* __restrict__ src,
                            const int* __restrict__ csr, int* __restrict__ cursor,
                            int* __restrict__ eid, int* __restrict__ srcS) {
    int e = blockIdx.x * 256 + threadIdx.x;
    if (e < NE) {
        int d = dst[e];
        int p = csr[d] + atomicAdd(&cursor[d], 1);
        eid[p] = e;
        srcS[p] = src[e];
    }
}

// ---------------------------------------------------------------------------
// Aggregation: wave per dst node, lane = 2 channels, zy in bf16 ([z|y] rows).
// x[n] += sum relu(z[src] + y[n] + ea@W3); epilogue emits bf16 hi/lo of x.
// ---------------------------------------------------------------------------
__global__ __launch_bounds__(256) void agg_kernel(
    float* __restrict__ x, const ushort* __restrict__ zy,
    const float* __restrict__ ea, const float* __restrict__ W3,
    const int* __restrict__ eid, const int* __restrict__ srcS,
    const int* __restrict__ csr, ushort* __restrict__ xh, ushort* __restrict__ xl,
    int emitSplit)
{
    int wid  = (blockIdx.x * 256 + threadIdx.x) >> 6;
    int lane = threadIdx.x & 63;
    if (wid >= NN) return;
    int c0 = lane * 2;

    float w00 = W3[0 * HIDD + c0],     w01 = W3[1 * HIDD + c0];
    float w02 = W3[2 * HIDD + c0],     w03 = W3[3 * HIDD + c0];
    float w10 = W3[0 * HIDD + c0 + 1], w11 = W3[1 * HIDD + c0 + 1];
    float w12 = W3[2 * HIDD + c0 + 1], w13 = W3[3 * HIDD + c0 + 1];

    ushort2 yu = *(const ushort2*)&zy[(size_t)wid * 256 + 128 + c0];
    float yx = bf2f(yu.x), yy = bf2f(yu.y);
    float2 acc = *(const float2*)&x[(size_t)wid * HIDD + c0];

    int i = csr[wid], end = csr[wid + 1];

    for (; i + 3 < end; i += 4) {
        int s0 = srcS[i], s1 = srcS[i + 1], s2 = srcS[i + 2], s3 = srcS[i + 3];
        int e0 = eid[i],  e1 = eid[i + 1],  e2 = eid[i + 2],  e3 = eid[i + 3];
        ushort2 z0 = *(const ushort2*)&zy[(size_t)s0 * 256 + c0];
        ushort2 z1 = *(const ushort2*)&zy[(size_t)s1 * 256 + c0];
        ushort2 z2 = *(const ushort2*)&zy[(size_t)s2 * 256 + c0];
        ushort2 z3 = *(const ushort2*)&zy[(size_t)s3 * 256 + c0];
        float4 a0 = *(const float4*)&ea[(size_t)e0 * EDIM];
        float4 a1 = *(const float4*)&ea[(size_t)e1 * EDIM];
        float4 a2 = *(const float4*)&ea[(size_t)e2 * EDIM];
        float4 a3 = *(const float4*)&ea[(size_t)e3 * EDIM];

        float m;
        m = bf2f(z0.x) + yx + a0.x * w00 + a0.y * w01 + a0.z * w02 + a0.w * w03; acc.x += fmaxf(m, 0.f);
        m = bf2f(z0.y) + yy + a0.x * w10 + a0.y * w11 + a0.z * w12 + a0.w * w13; acc.y += fmaxf(m, 0.f);
        m = bf2f(z1.x) + yx + a1.x * w00 + a1.y * w01 + a1.z * w02 + a1.w * w03; acc.x += fmaxf(m, 0.f);
        m = bf2f(z1.y) + yy + a1.x * w10 + a1.y * w11 + a1.z * w12 + a1.w * w13; acc.y += fmaxf(m, 0.f);
        m = bf2f(z2.x) + yx + a2.x * w00 + a2.y * w01 + a2.z * w02 + a2.w * w03; acc.x += fmaxf(m, 0.f);
        m = bf2f(z2.y) + yy + a2.x * w10 + a2.y * w11 + a2.z * w12 + a2.w * w13; acc.y += fmaxf(m, 0.f);
        m = bf2f(z3.x) + yx + a3.x * w00 + a3.y * w01 + a3.z * w02 + a3.w * w03; acc.x += fmaxf(m, 0.f);
        m = bf2f(z3.y) + yy + a3.x * w10 + a3.y * w11 + a3.z * w12 + a3.w * w13; acc.y += fmaxf(m, 0.f);
    }
    for (; i < end; i++) {
        int s = srcS[i];
        int e = eid[i];
        ushort2 zu = *(const ushort2*)&zy[(size_t)s * 256 + c0];
        float4 a  = *(const float4*)&ea[(size_t)e * EDIM];
        float m0 = bf2f(zu.x) + yx + a.x * w00 + a.y * w01 + a.z * w02 + a.w * w03;
        float m1 = bf2f(zu.y) + yy + a.x * w10 + a.y * w11 + a.z * w12 + a.w * w13;
        acc.x += fmaxf(m0, 0.f);
        acc.y += fmaxf(m1, 0.f);
    }
    *(float2*)&x[(size_t)wid * HIDD + c0] = acc;
    if (emitSplit) {
        ushort h0 = f2bf(acc.x), h1 = f2bf(acc.y);
        *(ushort2*)&xh[(size_t)wid * HIDD + c0] = make_ushort2(h0, h1);
        *(ushort2*)&xl[(size_t)wid * HIDD + c0] =
            make_ushort2(f2bf(acc.x - bf2f(h0)), f2bf(acc.y - bf2f(h1)));
    }
}

// ---------------------------------------------------------------------------
// Output projection: out[n] = x[n] @ W_out + b_out
// ---------------------------------------------------------------------------
__global__ __launch_bounds__(256) void out_kernel(
    const float* __restrict__ x, const float* __restrict__ Wo,
    const float* __restrict__ bo, float* __restrict__ out)
{
    int wid  = (blockIdx.x * 256 + threadIdx.x) >> 6;
    int lane = threadIdx.x & 63;
    if (wid >= NN) return;
    float2 xv = *(const float2*)&x[(size_t)wid * HIDD + lane * 2];
#pragma unroll
    for (int c = 0; c < ODIM; c++) {
        float p = xv.x * Wo[(lane * 2) * ODIM + c] + xv.y * Wo[(lane * 2 + 1) * ODIM + c];
#pragma unroll
        for (int off = 32; off; off >>= 1) p += __shfl_xor(p, off);
        if (lane == 0) out[(size_t)wid * ODIM + c] = p + bo[c];
    }
}

// ---------------------------------------------------------------------------
extern "C" void kernel_launch(void* const* d_in, const int* in_sizes, int n_in,
                              void* d_out, int out_size, void* d_ws, size_t ws_size,
                              hipStream_t stream)
{
    const float* h     = (const float*)d_in[0];
    const int*   ei    = (const int*)  d_in[1];
    const float* ea    = (const float*)d_in[2];
    const float* W_in  = (const float*)d_in[3];
    const float* b_in  = (const float*)d_in[4];
    const float* W_msg = (const float*)d_in[5];
    const float* b_msg = (const float*)d_in[6];
    const float* W_out = (const float*)d_in[7];
    const float* b_out = (const float*)d_in[8];
    float* out = (float*)d_out;

    // workspace carve-up (~84.5 MB)
    float*  x      = (float*)d_ws;                         // 6,400,000 f
    ushort* zy     = (ushort*)(x + 6400000);               // 12,800,000 us (aliased as h-stage)
    ushort* xh     = zy + 12800000;                        // 6,400,000 us
    ushort* xl     = xh + 6400000;                         // 6,400,000 us
    ushort* winTh  = xl + 6400000;                         // 32768
    ushort* winTl  = winTh + 32768;                        // 32768
    ushort* wzyTh  = winTl + 32768;                        // 131072
    ushort* wzyTl  = wzyTh + 131072;                       // 131072
    float*  bias256= (float*)(wzyTl + 131072);             // 1024 f
    int*    deg    = (int*)(bias256 + 1024);
    int*    cursor = deg + 50048;
    int*    csr    = cursor + 50048;                       // NN+1 used
    int*    eidArr = csr + 50048;
    int*    srcS   = eidArr + NE;
    int*    bsum   = srcS + NE;
    int*    boff   = bsum + 256;

    const int* srcA = ei;        // edge_index[0]
    const int* dstA = ei + NE;   // edge_index[1]

    // weight prep (tiny)
    conv_win<<<128, 256, 0, stream>>>(W_in, winTh, winTl);
    conv_wzy<<<512, 256, 0, stream>>>(W_msg, b_msg, wzyTh, wzyTl, bias256);

    // CSR build
    zero2_kernel<<<196, 256, 0, stream>>>(deg, cursor);
    hist_kernel <<<3125, 256, 0, stream>>>(dstA, deg);
    scan1_kernel<<<196, 256, 0, stream>>>(deg, csr, bsum);
    scan2_kernel<<<1, 256, 0, stream>>>(bsum, boff);
    scan3_kernel<<<196, 256, 0, stream>>>(csr, boff);
    fill_kernel <<<3125, 256, 0, stream>>>(dstA, srcA, csr, cursor, eidArr, srcS);

    // input projection, exact 3-term split, staged in zy region:
    // pass1: x = hh@(Wh+Wl) + b_in ; pass2: x += hl@Wh, emit xh/xl
    ushort* hstage = zy;
    conv_h_hi<<<12500, 256, 0, stream>>>(h, hstage);
    gemm_mfma<<<dim3(1, 391), 256, 0, stream>>>(
        hstage, nullptr, winTh, winTl, b_in,
        x, nullptr, nullptr, nullptr,
        NN, INDIM, INDIM, INDIM, HIDD, 0, 1, 0);
    conv_h_lo<<<12500, 256, 0, stream>>>(h, hstage);
    gemm_mfma<<<dim3(1, 391), 256, 0, stream>>>(
        hstage, nullptr, winTh, nullptr, nullptr,
        x, nullptr, xh, xl,
        NN, INDIM, INDIM, INDIM, HIDD, 0, 0, 1);

    for (int l = 0; l < NLAYERS; l++) {
        // zy = x @ [W1|W2] + [0|b_msg], bf16 out, exact 3-term split input
        gemm_mfma<<<dim3(2, 391), 256, 0, stream>>>(
            xh, xl, wzyTh + (size_t)l * 32768, wzyTl + (size_t)l * 32768,
            bias256 + l * 256,
            nullptr, zy, nullptr, nullptr,
            NN, HIDD, HIDD, HIDD, 256, 1, 1, 0);
        agg_kernel<<<12500, 256, 0, stream>>>(
            x, zy, ea, W_msg + (size_t)l * 33280 + 256 * 128,
            eidArr, srcS, csr, xh, xl, (l < NLAYERS - 1) ? 1 : 0);
    }

    out_kernel<<<12500, 256, 0, stream>>>(x, W_out, b_out, out);
}

// Round 4
// 603.569 us; speedup vs baseline: 1.7643x; 1.1424x over previous
//
#include <hip/hip_runtime.h>

#define NN 50000
#define NE 800000
#define INDIM 256
#define HIDD 128
#define ODIM 3
#define EDIM 4
#define NLAYERS 4

typedef __attribute__((ext_vector_type(8))) short bf16x8;
typedef __attribute__((ext_vector_type(4))) float f32x4;

// round-to-nearest-even fp32 -> bf16 bits (finite inputs)
__device__ __forceinline__ ushort f2bf(float f) {
    unsigned int x = __float_as_uint(f);
    unsigned int r = (x + 0x7fffu + ((x >> 16) & 1u)) >> 16;
    return (ushort)r;
}
__device__ __forceinline__ float bf2f(ushort u) {
    return __uint_as_float(((unsigned int)u) << 16);
}

__device__ __forceinline__ bf16x8 loadA8(const ushort* p, bool ok) {
    if (ok) return *(const bf16x8*)p;
    bf16x8 z = {0, 0, 0, 0, 0, 0, 0, 0};
    return z;
}

// ---------------------------------------------------------------------------
// Weights-resident MFMA GEMM.
//   C[M,N] = Ah@Bh + Ah@Bl + Al@Bh (+bias), B^T [n][k] staged to LDS ONCE,
//   then a BARRIER-FREE k-loop: A frags straight from global (16B/lane,
//   wave-coalesced), B frags from LDS (pad K+8 -> 2-way bank alias = free).
// Block: 512 threads = 8 waves; wave = 32 rows x N; block = 256 rows.
// NJ = N/16 col-frags, KSTEPS = K/32.
// ---------------------------------------------------------------------------
template<int NJ, int KSTEPS>
__global__ __launch_bounds__(512, 2) void gemm_wres(
    const ushort* __restrict__ Ah, const ushort* __restrict__ Al,
    const ushort* __restrict__ BTh, const ushort* __restrict__ BTl,
    const float* __restrict__ bias,
    float* __restrict__ Cf, ushort* __restrict__ Cb,
    int M, int lda, int ldc)
{
    constexpr int K  = KSTEPS * 32;
    constexpr int N  = NJ * 16;
    constexpr int KP = K + 8;                 // padded LDS stride
    extern __shared__ ushort sB[];            // [2][N][KP]
    ushort* sBh = sB;
    ushort* sBl = sB + (size_t)N * KP;

    const int tid = threadIdx.x;

    // stage B hi/lo (once)
    constexpr int KC8 = K / 8;                // 16B chunks per row
    for (int idx = tid; idx < N * KC8; idx += 512) {
        int n  = idx / KC8;
        int kc = idx % KC8;
        *(int4*)&sBh[n * KP + kc * 8] = *(const int4*)&BTh[n * K + kc * 8];
        *(int4*)&sBl[n * KP + kc * 8] = *(const int4*)&BTl[n * K + kc * 8];
    }
    __syncthreads();

    const int lane = tid & 63;
    const int wv   = tid >> 6;                // 0..7
    const int lm   = lane & 15, quad = lane >> 4;
    const int rowBase = blockIdx.x * 256 + wv * 32;

    f32x4 acc[2][NJ];
#pragma unroll
    for (int i = 0; i < 2; i++)
#pragma unroll
        for (int j = 0; j < NJ; j++)
#pragma unroll
            for (int t = 0; t < 4; t++) acc[i][j][t] = 0.f;

    for (int ks = 0; ks < KSTEPS; ks++) {
        const int ko = ks * 32 + quad * 8;
        bf16x8 ah[2], al[2];
#pragma unroll
        for (int i = 0; i < 2; i++) {
            int r = rowBase + i * 16 + lm;
            bool ok = r < M;
            size_t ao = (size_t)r * lda + ko;
            ah[i] = loadA8(&Ah[ao], ok);
            al[i] = loadA8(&Al[ao], ok);
        }
#pragma unroll
        for (int j = 0; j < NJ; j++) {
            int bo = (j * 16 + lm) * KP + ko;
            bf16x8 bh = *(const bf16x8*)&sBh[bo];
            bf16x8 bl = *(const bf16x8*)&sBl[bo];
            acc[0][j] = __builtin_amdgcn_mfma_f32_16x16x32_bf16(ah[0], bh, acc[0][j], 0, 0, 0);
            acc[1][j] = __builtin_amdgcn_mfma_f32_16x16x32_bf16(ah[1], bh, acc[1][j], 0, 0, 0);
            acc[0][j] = __builtin_amdgcn_mfma_f32_16x16x32_bf16(ah[0], bl, acc[0][j], 0, 0, 0);
            acc[1][j] = __builtin_amdgcn_mfma_f32_16x16x32_bf16(ah[1], bl, acc[1][j], 0, 0, 0);
            acc[0][j] = __builtin_amdgcn_mfma_f32_16x16x32_bf16(al[0], bh, acc[0][j], 0, 0, 0);
            acc[1][j] = __builtin_amdgcn_mfma_f32_16x16x32_bf16(al[1], bh, acc[1][j], 0, 0, 0);
        }
    }

    float bj[NJ];
#pragma unroll
    for (int j = 0; j < NJ; j++) bj[j] = bias ? bias[j * 16 + lm] : 0.f;

    // C/D layout: col = lane&15, row = quad*4 + reg
#pragma unroll
    for (int i = 0; i < 2; i++) {
#pragma unroll
        for (int t = 0; t < 4; t++) {
            int gr = rowBase + i * 16 + quad * 4 + t;
            if (gr < M) {
#pragma unroll
                for (int j = 0; j < NJ; j++) {
                    int gc = j * 16 + lm;
                    float v = acc[i][j][t] + bj[j];
                    size_t ci = (size_t)gr * ldc + gc;
                    if (Cb) Cb[ci] = f2bf(v);
                    else    Cf[ci] = v;
                }
            }
        }
    }
}

// ---------------------------------------------------------------------------
// conversion / prep kernels
// ---------------------------------------------------------------------------
__global__ void conv_h_both(const float* __restrict__ h, ushort* __restrict__ hh,
                            ushort* __restrict__ hl) {
    int id = blockIdx.x * 256 + threadIdx.x;            // 3.2M float4
    float4 v = *(const float4*)&h[(size_t)id * 4];
    ushort4 hi, lo;
    hi.x = f2bf(v.x); lo.x = f2bf(v.x - bf2f(hi.x));
    hi.y = f2bf(v.y); lo.y = f2bf(v.y - bf2f(hi.y));
    hi.z = f2bf(v.z); lo.z = f2bf(v.z - bf2f(hi.z));
    hi.w = f2bf(v.w); lo.w = f2bf(v.w - bf2f(hi.w));
    *(ushort4*)&hh[(size_t)id * 4] = hi;
    *(ushort4*)&hl[(size_t)id * 4] = lo;
}

__global__ void split_x(const float* __restrict__ x, ushort* __restrict__ xh,
                        ushort* __restrict__ xl) {
    int id = blockIdx.x * 256 + threadIdx.x;            // 1.6M float4
    float4 v = *(const float4*)&x[(size_t)id * 4];
    ushort4 hi, lo;
    hi.x = f2bf(v.x); lo.x = f2bf(v.x - bf2f(hi.x));
    hi.y = f2bf(v.y); lo.y = f2bf(v.y - bf2f(hi.y));
    hi.z = f2bf(v.z); lo.z = f2bf(v.z - bf2f(hi.z));
    hi.w = f2bf(v.w); lo.w = f2bf(v.w - bf2f(hi.w));
    *(ushort4*)&xh[(size_t)id * 4] = hi;
    *(ushort4*)&xl[(size_t)id * 4] = lo;
}

__global__ void conv_win(const float* __restrict__ W, ushort* __restrict__ Th,
                         ushort* __restrict__ Tl) {
    int id = blockIdx.x * 256 + threadIdx.x;            // 32768
    int k = id >> 7, n = id & 127;
    float v = W[id];
    ushort hi = f2bf(v);
    Th[n * 256 + k] = hi;
    Tl[n * 256 + k] = f2bf(v - bf2f(hi));
}

// build B^T [n][k] for fused [W1|W2] (N=256,K=128) per layer + bias256
__global__ void conv_wzy(const float* __restrict__ Wm, const float* __restrict__ bm,
                         ushort* __restrict__ Th, ushort* __restrict__ Tl,
                         float* __restrict__ b256) {
    int id = blockIdx.x * 256 + threadIdx.x;            // 131072
    int l = id >> 15;
    int r = id & 32767;
    int n = r >> 7, k = r & 127;
    float v = (n < 128) ? Wm[l * 33280 + k * 128 + n]
                        : Wm[l * 33280 + (128 + k) * 128 + (n - 128)];
    ushort hi = f2bf(v);
    size_t o = (size_t)l * 32768 + (size_t)n * 128 + k;
    Th[o] = hi;
    Tl[o] = f2bf(v - bf2f(hi));
    if (k == 0) b256[l * 256 + n] = (n < 128) ? 0.f : bm[l * 128 + (n - 128)];
}

// ---------------------------------------------------------------------------
// CSR build
// ---------------------------------------------------------------------------
__global__ void zero2_kernel(int* __restrict__ a, int* __restrict__ b) {
    int n = blockIdx.x * 256 + threadIdx.x;
    if (n < NN) { a[n] = 0; b[n] = 0; }
}

__global__ void hist_kernel(const int* __restrict__ dst, int* __restrict__ deg) {
    int e = blockIdx.x * 256 + threadIdx.x;
    if (e < NE) atomicAdd(&deg[dst[e]], 1);
}

__global__ void scan1_kernel(const int* __restrict__ deg, int* __restrict__ csr,
                             int* __restrict__ bsum) {
    __shared__ int s[256];
    int t = threadIdx.x;
    int n = blockIdx.x * 256 + t;
    int v = (n < NN) ? deg[n] : 0;
    s[t] = v; __syncthreads();
    for (int d = 1; d < 256; d <<= 1) {
        int u = (t >= d) ? s[t - d] : 0;
        __syncthreads();
        s[t] += u;
        __syncthreads();
    }
    if (n < NN) csr[n] = s[t] - v;
    if (t == 255) bsum[blockIdx.x] = s[t];
}

__global__ void scan2_kernel(const int* __restrict__ bsum, int* __restrict__ boff) {
    __shared__ int s[256];
    int t = threadIdx.x;
    int v = (t < 196) ? bsum[t] : 0;
    s[t] = v; __syncthreads();
    for (int d = 1; d < 256; d <<= 1) {
        int u = (t >= d) ? s[t - d] : 0;
        __syncthreads();
        s[t] += u;
        __syncthreads();
    }
    boff[t] = s[t] - v;
}

__global__ void scan3_kernel(int* __restrict__ csr, const int* __restrict__ boff) {
    int n = blockIdx.x * 256 + threadIdx.x;
    if (n < NN) csr[n] += boff[blockIdx.x];
    if (n == 0) csr[NN] = NE;
}

__global__ void fill_kernel(const int* __restrict__ dst, const int* __restrict__ src,
                            const int* __restrict__ csr, int* __restrict__ cursor,
                            int* __restrict__ eid, int* __restrict__ srcS) {
    int e = blockIdx.x * 256 + threadIdx.x;
    if (e < NE) {
        int d = dst[e];
        int p = csr[d] + atomicAdd(&cursor[d], 1);
        eid[p] = e;
        srcS[p] = src[e];
    }
}

// ---------------------------------------------------------------------------
// Aggregation: wave per dst node, lane = 2 channels, zy in bf16 ([z|y] rows).
// x[n] += sum relu(z[src] + y[n] + ea@W3); epilogue emits bf16 hi/lo of x.
// ---------------------------------------------------------------------------
__global__ __launch_bounds__(256) void agg_kernel(
    float* __restrict__ x, const ushort* __restrict__ zy,
    const float* __restrict__ ea, const float* __restrict__ W3,
    const int* __restrict__ eid, const int* __restrict__ srcS,
    const int* __restrict__ csr, ushort* __restrict__ xh, ushort* __restrict__ xl,
    int emitSplit)
{
    int wid  = (blockIdx.x * 256 + threadIdx.x) >> 6;
    int lane = threadIdx.x & 63;
    if (wid >= NN) return;
    int c0 = lane * 2;

    float w00 = W3[0 * HIDD + c0],     w01 = W3[1 * HIDD + c0];
    float w02 = W3[2 * HIDD + c0],     w03 = W3[3 * HIDD + c0];
    float w10 = W3[0 * HIDD + c0 + 1], w11 = W3[1 * HIDD + c0 + 1];
    float w12 = W3[2 * HIDD + c0 + 1], w13 = W3[3 * HIDD + c0 + 1];

    ushort2 yu = *(const ushort2*)&zy[(size_t)wid * 256 + 128 + c0];
    float yx = bf2f(yu.x), yy = bf2f(yu.y);
    float2 acc = *(const float2*)&x[(size_t)wid * HIDD + c0];

    int i = csr[wid], end = csr[wid + 1];

    for (; i + 3 < end; i += 4) {
        int s0 = srcS[i], s1 = srcS[i + 1], s2 = srcS[i + 2], s3 = srcS[i + 3];
        int e0 = eid[i],  e1 = eid[i + 1],  e2 = eid[i + 2],  e3 = eid[i + 3];
        ushort2 z0 = *(const ushort2*)&zy[(size_t)s0 * 256 + c0];
        ushort2 z1 = *(const ushort2*)&zy[(size_t)s1 * 256 + c0];
        ushort2 z2 = *(const ushort2*)&zy[(size_t)s2 * 256 + c0];
        ushort2 z3 = *(const ushort2*)&zy[(size_t)s3 * 256 + c0];
        float4 a0 = *(const float4*)&ea[(size_t)e0 * EDIM];
        float4 a1 = *(const float4*)&ea[(size_t)e1 * EDIM];
        float4 a2 = *(const float4*)&ea[(size_t)e2 * EDIM];
        float4 a3 = *(const float4*)&ea[(size_t)e3 * EDIM];

        float m;
        m = bf2f(z0.x) + yx + a0.x * w00 + a0.y * w01 + a0.z * w02 + a0.w * w03; acc.x += fmaxf(m, 0.f);
        m = bf2f(z0.y) + yy + a0.x * w10 + a0.y * w11 + a0.z * w12 + a0.w * w13; acc.y += fmaxf(m, 0.f);
        m = bf2f(z1.x) + yx + a1.x * w00 + a1.y * w01 + a1.z * w02 + a1.w * w03; acc.x += fmaxf(m, 0.f);
        m = bf2f(z1.y) + yy + a1.x * w10 + a1.y * w11 + a1.z * w12 + a1.w * w13; acc.y += fmaxf(m, 0.f);
        m = bf2f(z2.x) + yx + a2.x * w00 + a2.y * w01 + a2.z * w02 + a2.w * w03; acc.x += fmaxf(m, 0.f);
        m = bf2f(z2.y) + yy + a2.x * w10 + a2.y * w11 + a2.z * w12 + a2.w * w13; acc.y += fmaxf(m, 0.f);
        m = bf2f(z3.x) + yx + a3.x * w00 + a3.y * w01 + a3.z * w02 + a3.w * w03; acc.x += fmaxf(m, 0.f);
        m = bf2f(z3.y) + yy + a3.x * w10 + a3.y * w11 + a3.z * w12 + a3.w * w13; acc.y += fmaxf(m, 0.f);
    }
    for (; i < end; i++) {
        int s = srcS[i];
        int e = eid[i];
        ushort2 zu = *(const ushort2*)&zy[(size_t)s * 256 + c0];
        float4 a  = *(const float4*)&ea[(size_t)e * EDIM];
        float m0 = bf2f(zu.x) + yx + a.x * w00 + a.y * w01 + a.z * w02 + a.w * w03;
        float m1 = bf2f(zu.y) + yy + a.x * w10 + a.y * w11 + a.z * w12 + a.w * w13;
        acc.x += fmaxf(m0, 0.f);
        acc.y += fmaxf(m1, 0.f);
    }
    *(float2*)&x[(size_t)wid * HIDD + c0] = acc;
    if (emitSplit) {
        ushort h0 = f2bf(acc.x), h1 = f2bf(acc.y);
        *(ushort2*)&xh[(size_t)wid * HIDD + c0] = make_ushort2(h0, h1);
        *(ushort2*)&xl[(size_t)wid * HIDD + c0] =
            make_ushort2(f2bf(acc.x - bf2f(h0)), f2bf(acc.y - bf2f(h1)));
    }
}

// ---------------------------------------------------------------------------
// Output projection: out[n] = x[n] @ W_out + b_out
// ---------------------------------------------------------------------------
__global__ __launch_bounds__(256) void out_kernel(
    const float* __restrict__ x, const float* __restrict__ Wo,
    const float* __restrict__ bo, float* __restrict__ out)
{
    int wid  = (blockIdx.x * 256 + threadIdx.x) >> 6;
    int lane = threadIdx.x & 63;
    if (wid >= NN) return;
    float2 xv = *(const float2*)&x[(size_t)wid * HIDD + lane * 2];
#pragma unroll
    for (int c = 0; c < ODIM; c++) {
        float p = xv.x * Wo[(lane * 2) * ODIM + c] + xv.y * Wo[(lane * 2 + 1) * ODIM + c];
#pragma unroll
        for (int off = 32; off; off >>= 1) p += __shfl_xor(p, off);
        if (lane == 0) out[(size_t)wid * ODIM + c] = p + bo[c];
    }
}

// ---------------------------------------------------------------------------
extern "C" void kernel_launch(void* const* d_in, const int* in_sizes, int n_in,
                              void* d_out, int out_size, void* d_ws, size_t ws_size,
                              hipStream_t stream)
{
    const float* h     = (const float*)d_in[0];
    const int*   ei    = (const int*)  d_in[1];
    const float* ea    = (const float*)d_in[2];
    const float* W_in  = (const float*)d_in[3];
    const float* b_in  = (const float*)d_in[4];
    const float* W_msg = (const float*)d_in[5];
    const float* b_msg = (const float*)d_in[6];
    const float* W_out = (const float*)d_in[7];
    const float* b_out = (const float*)d_in[8];
    float* out = (float*)d_out;

    // workspace carve-up (~84.5 MB)
    float*  x      = (float*)d_ws;                         // 6,400,000 f
    ushort* zy     = (ushort*)(x + 6400000);               // 12,800,000 us
    ushort* xh     = zy + 12800000;                        // 6,400,000 us
    ushort* xl     = xh + 6400000;                         // 6,400,000 us
    ushort* winTh  = xl + 6400000;                         // 32768
    ushort* winTl  = winTh + 32768;                        // 32768
    ushort* wzyTh  = winTl + 32768;                        // 131072
    ushort* wzyTl  = wzyTh + 131072;                       // 131072
    float*  bias256= (float*)(wzyTl + 131072);             // 1024 f
    int*    deg    = (int*)(bias256 + 1024);
    int*    cursor = deg + 50048;
    int*    csr    = cursor + 50048;                       // NN+1 used
    int*    eidArr = csr + 50048;
    int*    srcS   = eidArr + NE;
    int*    bsum   = srcS + NE;
    int*    boff   = bsum + 256;

    const int* srcA = ei;        // edge_index[0]
    const int* dstA = ei + NE;   // edge_index[1]

    // allow >64KB dynamic LDS for the weights-resident GEMM
    hipFuncSetAttribute((const void*)&gemm_wres<16, 4>,
                        hipFuncAttributeMaxDynamicSharedMemorySize, 2 * 256 * 136 * 2);
    hipFuncSetAttribute((const void*)&gemm_wres<8, 8>,
                        hipFuncAttributeMaxDynamicSharedMemorySize, 2 * 128 * 264 * 2);

    // weight prep (tiny)
    conv_win<<<128, 256, 0, stream>>>(W_in, winTh, winTl);
    conv_wzy<<<512, 256, 0, stream>>>(W_msg, b_msg, wzyTh, wzyTl, bias256);

    // CSR build
    zero2_kernel<<<196, 256, 0, stream>>>(deg, cursor);
    hist_kernel <<<3125, 256, 0, stream>>>(dstA, deg);
    scan1_kernel<<<196, 256, 0, stream>>>(deg, csr, bsum);
    scan2_kernel<<<1, 256, 0, stream>>>(bsum, boff);
    scan3_kernel<<<196, 256, 0, stream>>>(csr, boff);
    fill_kernel <<<3125, 256, 0, stream>>>(dstA, srcA, csr, cursor, eidArr, srcS);

    // input projection: stage hh in zy region, hl in xh|xl region (contiguous),
    // one 3-term GEMM dispatch writes x fp32; then split x -> xh/xl.
    ushort* hh = zy;
    ushort* hl = xh;   // xh and xl are adjacent: 12.8M ushorts total
    conv_h_both<<<12500, 256, 0, stream>>>(h, hh, hl);
    gemm_wres<8, 8><<<196, 512, 2 * 128 * 264 * 2, stream>>>(
        hh, hl, winTh, winTl, b_in, x, nullptr, NN, INDIM, HIDD);
    split_x<<<6250, 256, 0, stream>>>(x, xh, xl);

    for (int l = 0; l < NLAYERS; l++) {
        // zy = x @ [W1|W2] + [0|b_msg], bf16 out, exact 3-term split
        gemm_wres<16, 4><<<196, 512, 2 * 256 * 136 * 2, stream>>>(
            xh, xl, wzyTh + (size_t)l * 32768, wzyTl + (size_t)l * 32768,
            bias256 + l * 256, nullptr, zy, NN, HIDD, 256);
        agg_kernel<<<12500, 256, 0, stream>>>(
            x, zy, ea, W_msg + (size_t)l * 33280 + 256 * 128,
            eidArr, srcS, csr, xh, xl, (l < NLAYERS - 1) ? 1 : 0);
    }

    out_kernel<<<12500, 256, 0, stream>>>(x, W_out, b_out, out);
}

// Round 5
// 581.035 us; speedup vs baseline: 1.8328x; 1.0388x over previous
//
#include <hip/hip_runtime.h>

#define NN 50000
#define NE 800000
#define INDIM 256
#define HIDD 128
#define ODIM 3
#define EDIM 4
#define NLAYERS 4

typedef __attribute__((ext_vector_type(8))) short bf16x8;
typedef __attribute__((ext_vector_type(4))) float f32x4;
typedef __attribute__((ext_vector_type(2))) float f32x2;

// round-to-nearest-even fp32 -> bf16 bits (finite inputs)
__device__ __forceinline__ ushort f2bf(float f) {
    unsigned int x = __float_as_uint(f);
    unsigned int r = (x + 0x7fffu + ((x >> 16) & 1u)) >> 16;
    return (ushort)r;
}
__device__ __forceinline__ float bf2f(ushort u) {
    return __uint_as_float(((unsigned int)u) << 16);
}
__device__ __forceinline__ float lo16f(unsigned int u) {
    return __uint_as_float(u << 16);
}
__device__ __forceinline__ float hi16f(unsigned int u) {
    return __uint_as_float(u & 0xffff0000u);
}

__device__ __forceinline__ bf16x8 loadA8(const ushort* p, bool ok) {
    if (ok) return *(const bf16x8*)p;
    bf16x8 z = {0, 0, 0, 0, 0, 0, 0, 0};
    return z;
}

// ---------------------------------------------------------------------------
// Weights-resident MFMA GEMM, N split across blockIdx.x so LDS <= ~70KB
// -> 2 blocks/CU, grid 2x196 = 392 blocks.
//   C = Ah@Bh + Ah@Bl + Al@Bh (+bias); B^T [n][k] staged to LDS once;
//   barrier-free k-loop; A frags straight from global (16B/lane coalesced).
// Block: 512 threads = 8 waves; wave = 32 rows x (NJ*16) cols.
// ---------------------------------------------------------------------------
template<int NJ, int KSTEPS>
__global__ __launch_bounds__(512, 4) void gemm_wres(
    const ushort* __restrict__ Ah, const ushort* __restrict__ Al,
    const ushort* __restrict__ BTh, const ushort* __restrict__ BTl,
    const float* __restrict__ bias,
    ushort* __restrict__ Cb,                      // bf16 C (zy mode) or null
    ushort* __restrict__ Eh, ushort* __restrict__ El,  // hi/lo split out (in-proj)
    int M, int lda, int ldc)
{
    constexpr int K  = KSTEPS * 32;
    constexpr int N  = NJ * 16;
    constexpr int KP = K + 8;                 // padded LDS stride (2-way alias = free)
    extern __shared__ ushort sB[];            // [2][N][KP]
    ushort* sBh = sB;
    ushort* sBl = sB + (size_t)N * KP;

    const int tid     = threadIdx.x;
    const int colBase = blockIdx.x * N;
    const ushort* Bh  = BTh + (size_t)colBase * K;
    const ushort* Bl  = BTl + (size_t)colBase * K;

    // stage B hi/lo once
    constexpr int KC8 = K / 8;
    for (int idx = tid; idx < N * KC8; idx += 512) {
        int n  = idx / KC8;
        int kc = idx % KC8;
        *(int4*)&sBh[n * KP + kc * 8] = *(const int4*)&Bh[(size_t)n * K + kc * 8];
        *(int4*)&sBl[n * KP + kc * 8] = *(const int4*)&Bl[(size_t)n * K + kc * 8];
    }
    __syncthreads();

    const int lane = tid & 63;
    const int wv   = tid >> 6;                // 0..7
    const int lm   = lane & 15, quad = lane >> 4;
    const int rowBase = blockIdx.y * 256 + wv * 32;

    f32x4 acc[2][NJ];
#pragma unroll
    for (int i = 0; i < 2; i++)
#pragma unroll
        for (int j = 0; j < NJ; j++)
#pragma unroll
            for (int t = 0; t < 4; t++) acc[i][j][t] = 0.f;

    for (int ks = 0; ks < KSTEPS; ks++) {
        const int ko = ks * 32 + quad * 8;
        bf16x8 ah[2], al[2];
#pragma unroll
        for (int i = 0; i < 2; i++) {
            int r = rowBase + i * 16 + lm;
            bool ok = r < M;
            size_t ao = (size_t)r * lda + ko;
            ah[i] = loadA8(&Ah[ao], ok);
            al[i] = loadA8(&Al[ao], ok);
        }
#pragma unroll
        for (int j = 0; j < NJ; j++) {
            int bo = (j * 16 + lm) * KP + ko;
            bf16x8 bh = *(const bf16x8*)&sBh[bo];
            bf16x8 bl = *(const bf16x8*)&sBl[bo];
            acc[0][j] = __builtin_amdgcn_mfma_f32_16x16x32_bf16(ah[0], bh, acc[0][j], 0, 0, 0);
            acc[1][j] = __builtin_amdgcn_mfma_f32_16x16x32_bf16(ah[1], bh, acc[1][j], 0, 0, 0);
            acc[0][j] = __builtin_amdgcn_mfma_f32_16x16x32_bf16(ah[0], bl, acc[0][j], 0, 0, 0);
            acc[1][j] = __builtin_amdgcn_mfma_f32_16x16x32_bf16(ah[1], bl, acc[1][j], 0, 0, 0);
            acc[0][j] = __builtin_amdgcn_mfma_f32_16x16x32_bf16(al[0], bh, acc[0][j], 0, 0, 0);
            acc[1][j] = __builtin_amdgcn_mfma_f32_16x16x32_bf16(al[1], bh, acc[1][j], 0, 0, 0);
        }
    }

    float bj[NJ];
#pragma unroll
    for (int j = 0; j < NJ; j++) bj[j] = bias ? bias[colBase + j * 16 + lm] : 0.f;

    // C/D layout: col = lane&15, row = quad*4 + reg
#pragma unroll
    for (int i = 0; i < 2; i++) {
#pragma unroll
        for (int t = 0; t < 4; t++) {
            int gr = rowBase + i * 16 + quad * 4 + t;
            if (gr < M) {
#pragma unroll
                for (int j = 0; j < NJ; j++) {
                    int gc = colBase + j * 16 + lm;
                    float v = acc[i][j][t] + bj[j];
                    size_t ci = (size_t)gr * ldc + gc;
                    if (Cb) {
                        Cb[ci] = f2bf(v);
                    } else {
                        ushort hi = f2bf(v);
                        Eh[ci] = hi;
                        El[ci] = f2bf(v - bf2f(hi));
                    }
                }
            }
        }
    }
}

// ---------------------------------------------------------------------------
// conversion / prep kernels
// ---------------------------------------------------------------------------
__global__ void conv_h_both(const float* __restrict__ h, ushort* __restrict__ hh,
                            ushort* __restrict__ hl) {
    int id = blockIdx.x * 256 + threadIdx.x;            // 3.2M float4
    float4 v = *(const float4*)&h[(size_t)id * 4];
    ushort4 hi, lo;
    hi.x = f2bf(v.x); lo.x = f2bf(v.x - bf2f(hi.x));
    hi.y = f2bf(v.y); lo.y = f2bf(v.y - bf2f(hi.y));
    hi.z = f2bf(v.z); lo.z = f2bf(v.z - bf2f(hi.z));
    hi.w = f2bf(v.w); lo.w = f2bf(v.w - bf2f(hi.w));
    *(ushort4*)&hh[(size_t)id * 4] = hi;
    *(ushort4*)&hl[(size_t)id * 4] = lo;
}

__global__ void conv_win(const float* __restrict__ W, ushort* __restrict__ Th,
                         ushort* __restrict__ Tl) {
    int id = blockIdx.x * 256 + threadIdx.x;            // 32768
    int k = id >> 7, n = id & 127;
    float v = W[id];
    ushort hi = f2bf(v);
    Th[n * 256 + k] = hi;
    Tl[n * 256 + k] = f2bf(v - bf2f(hi));
}

// build B^T [n][k] for fused [W1|W2] (N=256,K=128) per layer + bias256
__global__ void conv_wzy(const float* __restrict__ Wm, const float* __restrict__ bm,
                         ushort* __restrict__ Th, ushort* __restrict__ Tl,
                         float* __restrict__ b256) {
    int id = blockIdx.x * 256 + threadIdx.x;            // 131072
    int l = id >> 15;
    int r = id & 32767;
    int n = r >> 7, k = r & 127;
    float v = (n < 128) ? Wm[l * 33280 + k * 128 + n]
                        : Wm[l * 33280 + (128 + k) * 128 + (n - 128)];
    ushort hi = f2bf(v);
    size_t o = (size_t)l * 32768 + (size_t)n * 128 + k;
    Th[o] = hi;
    Tl[o] = f2bf(v - bf2f(hi));
    if (k == 0) b256[l * 256 + n] = (n < 128) ? 0.f : bm[l * 128 + (n - 128)];
}

// ---------------------------------------------------------------------------
// CSR build
// ---------------------------------------------------------------------------
__global__ void zero2_kernel(int* __restrict__ a, int* __restrict__ b) {
    int n = blockIdx.x * 256 + threadIdx.x;
    if (n < NN) { a[n] = 0; b[n] = 0; }
}

__global__ void hist_kernel(const int* __restrict__ dst, int* __restrict__ deg) {
    int e = blockIdx.x * 256 + threadIdx.x;
    if (e < NE) atomicAdd(&deg[dst[e]], 1);
}

__global__ void scan1_kernel(const int* __restrict__ deg, int* __restrict__ csr,
                             int* __restrict__ bsum) {
    __shared__ int s[256];
    int t = threadIdx.x;
    int n = blockIdx.x * 256 + t;
    int v = (n < NN) ? deg[n] : 0;
    s[t] = v; __syncthreads();
    for (int d = 1; d < 256; d <<= 1) {
        int u = (t >= d) ? s[t - d] : 0;
        __syncthreads();
        s[t] += u;
        __syncthreads();
    }
    if (n < NN) csr[n] = s[t] - v;
    if (t == 255) bsum[blockIdx.x] = s[t];
}

__global__ void scan2_kernel(const int* __restrict__ bsum, int* __restrict__ boff) {
    __shared__ int s[256];
    int t = threadIdx.x;
    int v = (t < 196) ? bsum[t] : 0;
    s[t] = v; __syncthreads();
    for (int d = 1; d < 256; d <<= 1) {
        int u = (t >= d) ? s[t - d] : 0;
        __syncthreads();
        s[t] += u;
        __syncthreads();
    }
    boff[t] = s[t] - v;
}

__global__ void scan3_kernel(int* __restrict__ csr, const int* __restrict__ boff) {
    int n = blockIdx.x * 256 + threadIdx.x;
    if (n < NN) csr[n] += boff[blockIdx.x];
    if (n == 0) csr[NN] = NE;
}

// fill: pre-gather src AND edge_attr into CSR order (kills eid indirection)
__global__ void fill_kernel(const int* __restrict__ dst, const int* __restrict__ src,
                            const float* __restrict__ ea,
                            const int* __restrict__ csr, int* __restrict__ cursor,
                            int* __restrict__ srcS, float* __restrict__ eaS) {
    int e = blockIdx.x * 256 + threadIdx.x;
    if (e < NE) {
        int d = dst[e];
        int p = csr[d] + atomicAdd(&cursor[d], 1);
        srcS[p] = src[e];
        *(float4*)&eaS[(size_t)p * 4] = *(const float4*)&ea[(size_t)e * 4];
    }
}

// ---------------------------------------------------------------------------
// Aggregation: wave per dst node, lane = 2 channels (packed-fp32 math).
// state x kept as exact bf16 hi/lo pair (xh+xl). zy rows = [z|y] bf16.
//   xnew[n] = x[n] + sum_e relu( z[src_e] + y[n] + eaS_e @ W3 )
// ---------------------------------------------------------------------------
__global__ __launch_bounds__(256) void agg_kernel(
    const ushort* __restrict__ zy, const float* __restrict__ eaS,
    const float* __restrict__ W3,
    const int* __restrict__ srcS, const int* __restrict__ csr,
    ushort* __restrict__ xh, ushort* __restrict__ xl)
{
    int wid  = (blockIdx.x * 256 + threadIdx.x) >> 6;
    int lane = threadIdx.x & 63;
    if (wid >= NN) return;
    int c0 = lane * 2;

    f32x2 w0 = {W3[0 * HIDD + c0], W3[0 * HIDD + c0 + 1]};
    f32x2 w1 = {W3[1 * HIDD + c0], W3[1 * HIDD + c0 + 1]};
    f32x2 w2 = {W3[2 * HIDD + c0], W3[2 * HIDD + c0 + 1]};
    f32x2 w3 = {W3[3 * HIDD + c0], W3[3 * HIDD + c0 + 1]};

    unsigned int uy = *(const unsigned int*)&zy[(size_t)wid * 256 + 128 + c0];
    f32x2 y2 = {lo16f(uy), hi16f(uy)};

    size_t xi = (size_t)wid * HIDD + c0;
    unsigned int uh = *(const unsigned int*)&xh[xi];
    unsigned int ul = *(const unsigned int*)&xl[xi];
    f32x2 acc = {lo16f(uh) + lo16f(ul), hi16f(uh) + hi16f(ul)};

    int i = csr[wid], end = csr[wid + 1];

    for (; i + 8 <= end; i += 8) {
        int s[8];
#pragma unroll
        for (int k = 0; k < 8; k++) s[k] = srcS[i + k];
        unsigned int zu[8];
#pragma unroll
        for (int k = 0; k < 8; k++)
            zu[k] = *(const unsigned int*)&zy[(size_t)s[k] * 256 + c0];
        float4 a[8];
#pragma unroll
        for (int k = 0; k < 8; k++)
            a[k] = *(const float4*)&eaS[(size_t)(i + k) * 4];
#pragma unroll
        for (int k = 0; k < 8; k++) {
            f32x2 m = {lo16f(zu[k]), hi16f(zu[k])};
            m += y2;
            m += a[k].x * w0;
            m += a[k].y * w1;
            m += a[k].z * w2;
            m += a[k].w * w3;
            acc.x += fmaxf(m.x, 0.f);
            acc.y += fmaxf(m.y, 0.f);
        }
    }
    for (; i < end; i++) {
        int sx = srcS[i];
        unsigned int zu = *(const unsigned int*)&zy[(size_t)sx * 256 + c0];
        float4 av = *(const float4*)&eaS[(size_t)i * 4];
        f32x2 m = {lo16f(zu), hi16f(zu)};
        m += y2;
        m += av.x * w0;
        m += av.y * w1;
        m += av.z * w2;
        m += av.w * w3;
        acc.x += fmaxf(m.x, 0.f);
        acc.y += fmaxf(m.y, 0.f);
    }

    ushort h0 = f2bf(acc.x), h1 = f2bf(acc.y);
    ushort l0 = f2bf(acc.x - bf2f(h0)), l1 = f2bf(acc.y - bf2f(h1));
    *(unsigned int*)&xh[xi] = (unsigned int)h0 | ((unsigned int)h1 << 16);
    *(unsigned int*)&xl[xi] = (unsigned int)l0 | ((unsigned int)l1 << 16);
}

// ---------------------------------------------------------------------------
// Output projection: out[n] = (xh+xl)[n] @ W_out + b_out
// ---------------------------------------------------------------------------
__global__ __launch_bounds__(256) void out_kernel(
    const ushort* __restrict__ xh, const ushort* __restrict__ xl,
    const float* __restrict__ Wo, const float* __restrict__ bo,
    float* __restrict__ out)
{
    int wid  = (blockIdx.x * 256 + threadIdx.x) >> 6;
    int lane = threadIdx.x & 63;
    if (wid >= NN) return;
    size_t xi = (size_t)wid * HIDD + lane * 2;
    unsigned int uh = *(const unsigned int*)&xh[xi];
    unsigned int ul = *(const unsigned int*)&xl[xi];
    float v0 = lo16f(uh) + lo16f(ul);
    float v1 = hi16f(uh) + hi16f(ul);
#pragma unroll
    for (int c = 0; c < ODIM; c++) {
        float p = v0 * Wo[(lane * 2) * ODIM + c] + v1 * Wo[(lane * 2 + 1) * ODIM + c];
#pragma unroll
        for (int off = 32; off; off >>= 1) p += __shfl_xor(p, off);
        if (lane == 0) out[(size_t)wid * ODIM + c] = p + bo[c];
    }
}

// ---------------------------------------------------------------------------
extern "C" void kernel_launch(void* const* d_in, const int* in_sizes, int n_in,
                              void* d_out, int out_size, void* d_ws, size_t ws_size,
                              hipStream_t stream)
{
    const float* h     = (const float*)d_in[0];
    const int*   ei    = (const int*)  d_in[1];
    const float* ea    = (const float*)d_in[2];
    const float* W_in  = (const float*)d_in[3];
    const float* b_in  = (const float*)d_in[4];
    const float* W_msg = (const float*)d_in[5];
    const float* b_msg = (const float*)d_in[6];
    const float* W_out = (const float*)d_in[7];
    const float* b_out = (const float*)d_in[8];
    float* out = (float*)d_out;

    // workspace carve-up (~77.5 MB)
    ushort* zy     = (ushort*)d_ws;                        // 12.8M us (hh stage, then zy)
    ushort* regB   = zy + 12800000;                        // 12.8M us (hl stage, then CSR/eaS)
    ushort* xh     = regB + 12800000;                      // 6.4M us
    ushort* xl     = xh + 6400000;                         // 6.4M us
    ushort* winTh  = xl + 6400000;                         // 32768
    ushort* winTl  = winTh + 32768;                        // 32768
    ushort* wzyTh  = winTl + 32768;                        // 131072
    ushort* wzyTl  = wzyTh + 131072;                       // 131072
    float*  bias256= (float*)(wzyTl + 131072);             // 1024 f

    // region B overlays (valid after in-proj GEMM completes)
    float* eaS    = (float*)regB;                          // 3.2M f
    int*   srcS   = (int*)(eaS + 3200000);                 // 800k
    int*   deg    = srcS + 800000;                         // 50176
    int*   cursor = deg + 50176;
    int*   csr    = cursor + 50176;                        // NN+1 used
    int*   bsum   = csr + 50176;                           // 256
    int*   boff   = bsum + 256;
    ushort* hl    = regB;                                  // in-proj staging alias

    const int* srcA = ei;        // edge_index[0]
    const int* dstA = ei + NE;   // edge_index[1]

    // allow >64KB dynamic LDS
    hipFuncSetAttribute((const void*)&gemm_wres<8, 4>,
                        hipFuncAttributeMaxDynamicSharedMemorySize, 2 * 128 * 136 * 2);
    hipFuncSetAttribute((const void*)&gemm_wres<4, 8>,
                        hipFuncAttributeMaxDynamicSharedMemorySize, 2 * 64 * 264 * 2);

    // weight prep (tiny)
    conv_win<<<128, 256, 0, stream>>>(W_in, winTh, winTl);
    conv_wzy<<<512, 256, 0, stream>>>(W_msg, b_msg, wzyTh, wzyTl, bias256);

    // input projection: hh -> zy, hl -> regB; one GEMM dispatch (2 col-halves),
    // epilogue emits xh/xl hi/lo split directly.
    conv_h_both<<<12500, 256, 0, stream>>>(h, zy, hl);
    gemm_wres<4, 8><<<dim3(2, 196), 512, 2 * 64 * 264 * 2, stream>>>(
        zy, hl, winTh, winTl, b_in, nullptr, xh, xl, NN, INDIM, HIDD);

    // CSR build (regB now free to overlay)
    zero2_kernel<<<196, 256, 0, stream>>>(deg, cursor);
    hist_kernel <<<3125, 256, 0, stream>>>(dstA, deg);
    scan1_kernel<<<196, 256, 0, stream>>>(deg, csr, bsum);
    scan2_kernel<<<1, 256, 0, stream>>>(bsum, boff);
    scan3_kernel<<<196, 256, 0, stream>>>(csr, boff);
    fill_kernel <<<3125, 256, 0, stream>>>(dstA, srcA, ea, csr, cursor, srcS, eaS);

    for (int l = 0; l < NLAYERS; l++) {
        // zy = (xh+xl) @ [W1|W2] + [0|b_msg], bf16 out
        gemm_wres<8, 4><<<dim3(2, 196), 512, 2 * 128 * 136 * 2, stream>>>(
            xh, xl, wzyTh + (size_t)l * 32768, wzyTl + (size_t)l * 32768,
            bias256 + l * 256, zy, nullptr, nullptr, NN, HIDD, 256);
        agg_kernel<<<12500, 256, 0, stream>>>(
            zy, eaS, W_msg + (size_t)l * 33280 + 256 * 128,
            srcS, csr, xh, xl);
    }

    out_kernel<<<12500, 256, 0, stream>>>(xh, xl, W_out, b_out, out);
}

// Round 6
// 555.649 us; speedup vs baseline: 1.9165x; 1.0457x over previous
//
#include <hip/hip_runtime.h>

#define NN 50000
#define NE 800000
#define INDIM 256
#define HIDD 128
#define ODIM 3
#define EDIM 4
#define NLAYERS 4

typedef __attribute__((ext_vector_type(8))) short bf16x8;
typedef __attribute__((ext_vector_type(4))) float f32x4;
typedef __attribute__((ext_vector_type(2))) float f32x2;

// round-to-nearest-even fp32 -> bf16 bits (finite inputs)
__device__ __forceinline__ ushort f2bf(float f) {
    unsigned int x = __float_as_uint(f);
    unsigned int r = (x + 0x7fffu + ((x >> 16) & 1u)) >> 16;
    return (ushort)r;
}
__device__ __forceinline__ float bf2f(ushort u) {
    return __uint_as_float(((unsigned int)u) << 16);
}
__device__ __forceinline__ float lo16f(unsigned int u) {
    return __uint_as_float(u << 16);
}
__device__ __forceinline__ float hi16f(unsigned int u) {
    return __uint_as_float(u & 0xffff0000u);
}

__device__ __forceinline__ bf16x8 loadA8(const ushort* p, bool ok) {
    if (ok) return *(const bf16x8*)p;
    bf16x8 z = {0, 0, 0, 0, 0, 0, 0, 0};
    return z;
}

// ---------------------------------------------------------------------------
// Weights-resident MFMA GEMM (bf16 hi/lo A in memory).
//   C = Ah@Bh + Ah@Bl + Al@Bh (+bias); B^T [n][k] staged to LDS once;
//   barrier-free k-loop; A frags straight from global (16B/lane coalesced).
// Block: 512 threads = 8 waves; wave = 32 rows x (NJ*16) cols; grid.x = N-split.
// ---------------------------------------------------------------------------
template<int NJ, int KSTEPS>
__global__ __launch_bounds__(512, 4) void gemm_wres(
    const ushort* __restrict__ Ah, const ushort* __restrict__ Al,
    const ushort* __restrict__ BTh, const ushort* __restrict__ BTl,
    const float* __restrict__ bias,
    ushort* __restrict__ Cb, int M, int lda, int ldc)
{
    constexpr int K  = KSTEPS * 32;
    constexpr int N  = NJ * 16;
    constexpr int KP = K + 8;                 // padded LDS stride (2-way alias = free)
    extern __shared__ ushort sB[];            // [2][N][KP]
    ushort* sBh = sB;
    ushort* sBl = sB + (size_t)N * KP;

    const int tid     = threadIdx.x;
    const int colBase = blockIdx.x * N;
    const ushort* Bh  = BTh + (size_t)colBase * K;
    const ushort* Bl  = BTl + (size_t)colBase * K;

    constexpr int KC8 = K / 8;
    for (int idx = tid; idx < N * KC8; idx += 512) {
        int n  = idx / KC8;
        int kc = idx % KC8;
        *(int4*)&sBh[n * KP + kc * 8] = *(const int4*)&Bh[(size_t)n * K + kc * 8];
        *(int4*)&sBl[n * KP + kc * 8] = *(const int4*)&Bl[(size_t)n * K + kc * 8];
    }
    __syncthreads();

    const int lane = tid & 63;
    const int wv   = tid >> 6;
    const int lm   = lane & 15, quad = lane >> 4;
    const int rowBase = blockIdx.y * 256 + wv * 32;

    f32x4 acc[2][NJ];
#pragma unroll
    for (int i = 0; i < 2; i++)
#pragma unroll
        for (int j = 0; j < NJ; j++)
#pragma unroll
            for (int t = 0; t < 4; t++) acc[i][j][t] = 0.f;

    for (int ks = 0; ks < KSTEPS; ks++) {
        const int ko = ks * 32 + quad * 8;
        bf16x8 ah[2], al[2];
#pragma unroll
        for (int i = 0; i < 2; i++) {
            int r = rowBase + i * 16 + lm;
            bool ok = r < M;
            size_t ao = (size_t)r * lda + ko;
            ah[i] = loadA8(&Ah[ao], ok);
            al[i] = loadA8(&Al[ao], ok);
        }
#pragma unroll
        for (int j = 0; j < NJ; j++) {
            int bo = (j * 16 + lm) * KP + ko;
            bf16x8 bh = *(const bf16x8*)&sBh[bo];
            bf16x8 bl = *(const bf16x8*)&sBl[bo];
            acc[0][j] = __builtin_amdgcn_mfma_f32_16x16x32_bf16(ah[0], bh, acc[0][j], 0, 0, 0);
            acc[1][j] = __builtin_amdgcn_mfma_f32_16x16x32_bf16(ah[1], bh, acc[1][j], 0, 0, 0);
            acc[0][j] = __builtin_amdgcn_mfma_f32_16x16x32_bf16(ah[0], bl, acc[0][j], 0, 0, 0);
            acc[1][j] = __builtin_amdgcn_mfma_f32_16x16x32_bf16(ah[1], bl, acc[1][j], 0, 0, 0);
            acc[0][j] = __builtin_amdgcn_mfma_f32_16x16x32_bf16(al[0], bh, acc[0][j], 0, 0, 0);
            acc[1][j] = __builtin_amdgcn_mfma_f32_16x16x32_bf16(al[1], bh, acc[1][j], 0, 0, 0);
        }
    }

    float bj[NJ];
#pragma unroll
    for (int j = 0; j < NJ; j++) bj[j] = bias ? bias[colBase + j * 16 + lm] : 0.f;

    // C/D layout: col = lane&15, row = quad*4 + reg
#pragma unroll
    for (int i = 0; i < 2; i++) {
#pragma unroll
        for (int t = 0; t < 4; t++) {
            int gr = rowBase + i * 16 + quad * 4 + t;
            if (gr < M) {
#pragma unroll
                for (int j = 0; j < NJ; j++) {
                    int gc = colBase + j * 16 + lm;
                    Cb[(size_t)gr * ldc + gc] = f2bf(acc[i][j][t] + bj[j]);
                }
            }
        }
    }
}

// ---------------------------------------------------------------------------
// In-projection GEMM: A is fp32 (h), hi/lo split done IN REGISTERS.
// Epilogue emits xh/xl exact hi/lo bf16 split. Same structure otherwise.
// ---------------------------------------------------------------------------
template<int NJ, int KSTEPS>
__global__ __launch_bounds__(512, 4) void gemm_wres_f32(
    const float* __restrict__ A,
    const ushort* __restrict__ BTh, const ushort* __restrict__ BTl,
    const float* __restrict__ bias,
    ushort* __restrict__ Eh, ushort* __restrict__ El,
    int M, int lda, int ldc)
{
    constexpr int K  = KSTEPS * 32;
    constexpr int N  = NJ * 16;
    constexpr int KP = K + 8;
    extern __shared__ ushort sB[];
    ushort* sBh = sB;
    ushort* sBl = sB + (size_t)N * KP;

    const int tid     = threadIdx.x;
    const int colBase = blockIdx.x * N;
    const ushort* Bh  = BTh + (size_t)colBase * K;
    const ushort* Bl  = BTl + (size_t)colBase * K;

    constexpr int KC8 = K / 8;
    for (int idx = tid; idx < N * KC8; idx += 512) {
        int n  = idx / KC8;
        int kc = idx % KC8;
        *(int4*)&sBh[n * KP + kc * 8] = *(const int4*)&Bh[(size_t)n * K + kc * 8];
        *(int4*)&sBl[n * KP + kc * 8] = *(const int4*)&Bl[(size_t)n * K + kc * 8];
    }
    __syncthreads();

    const int lane = tid & 63;
    const int wv   = tid >> 6;
    const int lm   = lane & 15, quad = lane >> 4;
    const int rowBase = blockIdx.y * 256 + wv * 32;

    f32x4 acc[2][NJ];
#pragma unroll
    for (int i = 0; i < 2; i++)
#pragma unroll
        for (int j = 0; j < NJ; j++)
#pragma unroll
            for (int t = 0; t < 4; t++) acc[i][j][t] = 0.f;

    for (int ks = 0; ks < KSTEPS; ks++) {
        const int ko = ks * 32 + quad * 8;
        bf16x8 ah[2], al[2];
#pragma unroll
        for (int i = 0; i < 2; i++) {
            int r = rowBase + i * 16 + lm;
            float v[8];
            if (r < M) {
                const float* ap = &A[(size_t)r * lda + ko];
                *(float4*)&v[0] = *(const float4*)ap;
                *(float4*)&v[4] = *(const float4*)(ap + 4);
            } else {
#pragma unroll
                for (int q = 0; q < 8; q++) v[q] = 0.f;
            }
#pragma unroll
            for (int q = 0; q < 8; q++) {
                ushort hi = f2bf(v[q]);
                ah[i][q] = (short)hi;
                al[i][q] = (short)f2bf(v[q] - bf2f(hi));
            }
        }
#pragma unroll
        for (int j = 0; j < NJ; j++) {
            int bo = (j * 16 + lm) * KP + ko;
            bf16x8 bh = *(const bf16x8*)&sBh[bo];
            bf16x8 bl = *(const bf16x8*)&sBl[bo];
            acc[0][j] = __builtin_amdgcn_mfma_f32_16x16x32_bf16(ah[0], bh, acc[0][j], 0, 0, 0);
            acc[1][j] = __builtin_amdgcn_mfma_f32_16x16x32_bf16(ah[1], bh, acc[1][j], 0, 0, 0);
            acc[0][j] = __builtin_amdgcn_mfma_f32_16x16x32_bf16(ah[0], bl, acc[0][j], 0, 0, 0);
            acc[1][j] = __builtin_amdgcn_mfma_f32_16x16x32_bf16(ah[1], bl, acc[1][j], 0, 0, 0);
            acc[0][j] = __builtin_amdgcn_mfma_f32_16x16x32_bf16(al[0], bh, acc[0][j], 0, 0, 0);
            acc[1][j] = __builtin_amdgcn_mfma_f32_16x16x32_bf16(al[1], bh, acc[1][j], 0, 0, 0);
        }
    }

    float bj[NJ];
#pragma unroll
    for (int j = 0; j < NJ; j++) bj[j] = bias ? bias[colBase + j * 16 + lm] : 0.f;

#pragma unroll
    for (int i = 0; i < 2; i++) {
#pragma unroll
        for (int t = 0; t < 4; t++) {
            int gr = rowBase + i * 16 + quad * 4 + t;
            if (gr < M) {
#pragma unroll
                for (int j = 0; j < NJ; j++) {
                    int gc = colBase + j * 16 + lm;
                    float v = acc[i][j][t] + bj[j];
                    size_t ci = (size_t)gr * ldc + gc;
                    ushort hi = f2bf(v);
                    Eh[ci] = hi;
                    El[ci] = f2bf(v - bf2f(hi));
                }
            }
        }
    }
}

// ---------------------------------------------------------------------------
// weight prep
// ---------------------------------------------------------------------------
__global__ void conv_win(const float* __restrict__ W, ushort* __restrict__ Th,
                         ushort* __restrict__ Tl) {
    int id = blockIdx.x * 256 + threadIdx.x;            // 32768
    int k = id >> 7, n = id & 127;
    float v = W[id];
    ushort hi = f2bf(v);
    Th[n * 256 + k] = hi;
    Tl[n * 256 + k] = f2bf(v - bf2f(hi));
}

__global__ void conv_wzy(const float* __restrict__ Wm, const float* __restrict__ bm,
                         ushort* __restrict__ Th, ushort* __restrict__ Tl,
                         float* __restrict__ b256) {
    int id = blockIdx.x * 256 + threadIdx.x;            // 131072
    int l = id >> 15;
    int r = id & 32767;
    int n = r >> 7, k = r & 127;
    float v = (n < 128) ? Wm[l * 33280 + k * 128 + n]
                        : Wm[l * 33280 + (128 + k) * 128 + (n - 128)];
    ushort hi = f2bf(v);
    size_t o = (size_t)l * 32768 + (size_t)n * 128 + k;
    Th[o] = hi;
    Tl[o] = f2bf(v - bf2f(hi));
    if (k == 0) b256[l * 256 + n] = (n < 128) ? 0.f : bm[l * 128 + (n - 128)];
}

// ---------------------------------------------------------------------------
// CSR build
// ---------------------------------------------------------------------------
__global__ void zero2_kernel(int* __restrict__ a, int* __restrict__ b) {
    int n = blockIdx.x * 256 + threadIdx.x;
    if (n < NN) { a[n] = 0; b[n] = 0; }
}

__global__ void hist_kernel(const int* __restrict__ dst, int* __restrict__ deg) {
    int e = blockIdx.x * 256 + threadIdx.x;
    if (e < NE) atomicAdd(&deg[dst[e]], 1);
}

__global__ void scan1_kernel(const int* __restrict__ deg, int* __restrict__ csr,
                             int* __restrict__ bsum) {
    __shared__ int s[256];
    int t = threadIdx.x;
    int n = blockIdx.x * 256 + t;
    int v = (n < NN) ? deg[n] : 0;
    s[t] = v; __syncthreads();
    for (int d = 1; d < 256; d <<= 1) {
        int u = (t >= d) ? s[t - d] : 0;
        __syncthreads();
        s[t] += u;
        __syncthreads();
    }
    if (n < NN) csr[n] = s[t] - v;
    if (t == 255) bsum[blockIdx.x] = s[t];
}

__global__ void scan2_kernel(const int* __restrict__ bsum, int* __restrict__ boff) {
    __shared__ int s[256];
    int t = threadIdx.x;
    int v = (t < 196) ? bsum[t] : 0;
    s[t] = v; __syncthreads();
    for (int d = 1; d < 256; d <<= 1) {
        int u = (t >= d) ? s[t - d] : 0;
        __syncthreads();
        s[t] += u;
        __syncthreads();
    }
    boff[t] = s[t] - v;
}

__global__ void scan3_kernel(int* __restrict__ csr, const int* __restrict__ boff) {
    int n = blockIdx.x * 256 + threadIdx.x;
    if (n < NN) csr[n] += boff[blockIdx.x];
    if (n == 0) csr[NN] = NE;
}

// fill: minimal scatter — only the 4B rank map eid[p]=e
__global__ void fill_kernel(const int* __restrict__ dst, const int* __restrict__ csr,
                            int* __restrict__ cursor, int* __restrict__ eid) {
    int e = blockIdx.x * 256 + threadIdx.x;
    if (e < NE) {
        int d = dst[e];
        int p = csr[d] + atomicAdd(&cursor[d], 1);
        eid[p] = e;
    }
}

// gather pass: coalesced writes of srcS/eaS in CSR order; random reads of
// src (3.2 MB) and ea (12.8 MB) served by L2/L3.
__global__ void gather_kernel(const int* __restrict__ eid, const int* __restrict__ src,
                              const float* __restrict__ ea,
                              int* __restrict__ srcS, float* __restrict__ eaS) {
    int p = blockIdx.x * 256 + threadIdx.x;
    if (p < NE) {
        int e = eid[p];
        srcS[p] = src[e];
        *(float4*)&eaS[(size_t)p * 4] = *(const float4*)&ea[(size_t)e * 4];
    }
}

// ---------------------------------------------------------------------------
// Aggregation: wave per dst node, lane = 2 channels (packed-fp32 math).
// state x = exact bf16 hi/lo pair (xh+xl). zy rows = [z|y] bf16.
// ---------------------------------------------------------------------------
__global__ __launch_bounds__(256) void agg_kernel(
    const ushort* __restrict__ zy, const float* __restrict__ eaS,
    const float* __restrict__ W3,
    const int* __restrict__ srcS, const int* __restrict__ csr,
    ushort* __restrict__ xh, ushort* __restrict__ xl)
{
    int wid  = (blockIdx.x * 256 + threadIdx.x) >> 6;
    int lane = threadIdx.x & 63;
    if (wid >= NN) return;
    int c0 = lane * 2;

    f32x2 w0 = {W3[0 * HIDD + c0], W3[0 * HIDD + c0 + 1]};
    f32x2 w1 = {W3[1 * HIDD + c0], W3[1 * HIDD + c0 + 1]};
    f32x2 w2 = {W3[2 * HIDD + c0], W3[2 * HIDD + c0 + 1]};
    f32x2 w3 = {W3[3 * HIDD + c0], W3[3 * HIDD + c0 + 1]};

    unsigned int uy = *(const unsigned int*)&zy[(size_t)wid * 256 + 128 + c0];
    f32x2 y2 = {lo16f(uy), hi16f(uy)};

    size_t xi = (size_t)wid * HIDD + c0;
    unsigned int uh = *(const unsigned int*)&xh[xi];
    unsigned int ul = *(const unsigned int*)&xl[xi];
    f32x2 acc = {lo16f(uh) + lo16f(ul), hi16f(uh) + hi16f(ul)};

    int i = csr[wid], end = csr[wid + 1];

    for (; i + 8 <= end; i += 8) {
        int s[8];
#pragma unroll
        for (int k = 0; k < 8; k++) s[k] = srcS[i + k];
        unsigned int zu[8];
#pragma unroll
        for (int k = 0; k < 8; k++)
            zu[k] = *(const unsigned int*)&zy[(size_t)s[k] * 256 + c0];
        float4 a[8];
#pragma unroll
        for (int k = 0; k < 8; k++)
            a[k] = *(const float4*)&eaS[(size_t)(i + k) * 4];
#pragma unroll
        for (int k = 0; k < 8; k++) {
            f32x2 m = {lo16f(zu[k]), hi16f(zu[k])};
            m += y2;
            m += a[k].x * w0;
            m += a[k].y * w1;
            m += a[k].z * w2;
            m += a[k].w * w3;
            acc.x += fmaxf(m.x, 0.f);
            acc.y += fmaxf(m.y, 0.f);
        }
    }
    for (; i < end; i++) {
        int sx = srcS[i];
        unsigned int zu = *(const unsigned int*)&zy[(size_t)sx * 256 + c0];
        float4 av = *(const float4*)&eaS[(size_t)i * 4];
        f32x2 m = {lo16f(zu), hi16f(zu)};
        m += y2;
        m += av.x * w0;
        m += av.y * w1;
        m += av.z * w2;
        m += av.w * w3;
        acc.x += fmaxf(m.x, 0.f);
        acc.y += fmaxf(m.y, 0.f);
    }

    ushort h0 = f2bf(acc.x), h1 = f2bf(acc.y);
    ushort l0 = f2bf(acc.x - bf2f(h0)), l1 = f2bf(acc.y - bf2f(h1));
    *(unsigned int*)&xh[xi] = (unsigned int)h0 | ((unsigned int)h1 << 16);
    *(unsigned int*)&xl[xi] = (unsigned int)l0 | ((unsigned int)l1 << 16);
}

// ---------------------------------------------------------------------------
// Output projection: out[n] = (xh+xl)[n] @ W_out + b_out
// ---------------------------------------------------------------------------
__global__ __launch_bounds__(256) void out_kernel(
    const ushort* __restrict__ xh, const ushort* __restrict__ xl,
    const float* __restrict__ Wo, const float* __restrict__ bo,
    float* __restrict__ out)
{
    int wid  = (blockIdx.x * 256 + threadIdx.x) >> 6;
    int lane = threadIdx.x & 63;
    if (wid >= NN) return;
    size_t xi = (size_t)wid * HIDD + lane * 2;
    unsigned int uh = *(const unsigned int*)&xh[xi];
    unsigned int ul = *(const unsigned int*)&xl[xi];
    float v0 = lo16f(uh) + lo16f(ul);
    float v1 = hi16f(uh) + hi16f(ul);
#pragma unroll
    for (int c = 0; c < ODIM; c++) {
        float p = v0 * Wo[(lane * 2) * ODIM + c] + v1 * Wo[(lane * 2 + 1) * ODIM + c];
#pragma unroll
        for (int off = 32; off; off >>= 1) p += __shfl_xor(p, off);
        if (lane == 0) out[(size_t)wid * ODIM + c] = p + bo[c];
    }
}

// ---------------------------------------------------------------------------
extern "C" void kernel_launch(void* const* d_in, const int* in_sizes, int n_in,
                              void* d_out, int out_size, void* d_ws, size_t ws_size,
                              hipStream_t stream)
{
    const float* h     = (const float*)d_in[0];
    const int*   ei    = (const int*)  d_in[1];
    const float* ea    = (const float*)d_in[2];
    const float* W_in  = (const float*)d_in[3];
    const float* b_in  = (const float*)d_in[4];
    const float* W_msg = (const float*)d_in[5];
    const float* b_msg = (const float*)d_in[6];
    const float* W_out = (const float*)d_in[7];
    const float* b_out = (const float*)d_in[8];
    float* out = (float*)d_out;

    // workspace carve-up (~78 MB)
    ushort* zy     = (ushort*)d_ws;                        // 12.8M us
    float*  eaS    = (float*)(zy + 12800000);              // 3.2M f
    int*    srcS   = (int*)(eaS + 3200000);                // 800k
    int*    eidArr = srcS + 800000;                        // 800k
    int*    deg    = eidArr + 800000;                      // 50176
    int*    cursor = deg + 50176;
    int*    csr    = cursor + 50176;                       // NN+1 used
    int*    bsum   = csr + 50176;                          // 256
    int*    boff   = bsum + 256;                           // 256
    ushort* xh     = (ushort*)(boff + 256);                // 6.4M us
    ushort* xl     = xh + 6400000;                         // 6.4M us
    ushort* winTh  = xl + 6400000;                         // 32768
    ushort* winTl  = winTh + 32768;                        // 32768
    ushort* wzyTh  = winTl + 32768;                        // 131072
    ushort* wzyTl  = wzyTh + 131072;                       // 131072
    float*  bias256= (float*)(wzyTl + 131072);             // 1024 f

    const int* srcA = ei;        // edge_index[0]
    const int* dstA = ei + NE;   // edge_index[1]

    // allow >64KB dynamic LDS
    hipFuncSetAttribute((const void*)&gemm_wres<8, 4>,
                        hipFuncAttributeMaxDynamicSharedMemorySize, 2 * 128 * 136 * 2);
    hipFuncSetAttribute((const void*)&gemm_wres_f32<4, 8>,
                        hipFuncAttributeMaxDynamicSharedMemorySize, 2 * 64 * 264 * 2);

    // weight prep (tiny)
    conv_win<<<128, 256, 0, stream>>>(W_in, winTh, winTl);
    conv_wzy<<<512, 256, 0, stream>>>(W_msg, b_msg, wzyTh, wzyTl, bias256);

    // CSR build: rank map only, then coalesced gather of srcS/eaS
    zero2_kernel<<<196, 256, 0, stream>>>(deg, cursor);
    hist_kernel <<<3125, 256, 0, stream>>>(dstA, deg);
    scan1_kernel<<<196, 256, 0, stream>>>(deg, csr, bsum);
    scan2_kernel<<<1, 256, 0, stream>>>(bsum, boff);
    scan3_kernel<<<196, 256, 0, stream>>>(csr, boff);
    fill_kernel <<<3125, 256, 0, stream>>>(dstA, csr, cursor, eidArr);
    gather_kernel<<<3125, 256, 0, stream>>>(eidArr, srcA, ea, srcS, eaS);

    // input projection straight from fp32 h (in-register hi/lo split)
    gemm_wres_f32<4, 8><<<dim3(2, 196), 512, 2 * 64 * 264 * 2, stream>>>(
        h, winTh, winTl, b_in, xh, xl, NN, INDIM, HIDD);

    for (int l = 0; l < NLAYERS; l++) {
        gemm_wres<8, 4><<<dim3(2, 196), 512, 2 * 128 * 136 * 2, stream>>>(
            xh, xl, wzyTh + (size_t)l * 32768, wzyTl + (size_t)l * 32768,
            bias256 + l * 256, zy, NN, HIDD, 256);
        agg_kernel<<<12500, 256, 0, stream>>>(
            zy, eaS, W_msg + (size_t)l * 33280 + 256 * 128,
            srcS, csr, xh, xl);
    }

    out_kernel<<<12500, 256, 0, stream>>>(xh, xl, W_out, b_out, out);
}

// Round 7
// 484.136 us; speedup vs baseline: 2.1996x; 1.1477x over previous
//
#include <hip/hip_runtime.h>

#define NN 50000
#define NE 800000
#define INDIM 256
#define HIDD 128
#define ODIM 3
#define EDIM 4
#define NLAYERS 4

typedef __attribute__((ext_vector_type(8))) short bf16x8;
typedef __attribute__((ext_vector_type(4))) float f32x4;
typedef __attribute__((ext_vector_type(2))) float f32x2;

// round-to-nearest-even fp32 -> bf16 bits (finite inputs)
__device__ __forceinline__ ushort f2bf(float f) {
    unsigned int x = __float_as_uint(f);
    unsigned int r = (x + 0x7fffu + ((x >> 16) & 1u)) >> 16;
    return (ushort)r;
}
__device__ __forceinline__ float bf2f(ushort u) {
    return __uint_as_float(((unsigned int)u) << 16);
}
__device__ __forceinline__ float lo16f(unsigned int u) {
    return __uint_as_float(u << 16);
}
__device__ __forceinline__ float hi16f(unsigned int u) {
    return __uint_as_float(u & 0xffff0000u);
}

__device__ __forceinline__ bf16x8 loadA8(const ushort* p, bool ok) {
    if (ok) return *(const bf16x8*)p;
    bf16x8 z = {0, 0, 0, 0, 0, 0, 0, 0};
    return z;
}

// XCD-pairing swizzle: 1D grid of 400; col-half pair (x=0/1, same y) differs
// by 8 in block id -> same XCD under round-robin assignment (perf-only hint).
__device__ __forceinline__ bool swizzle400(int b, int& x, int& y) {
    x = (b >> 3) & 1;
    y = (b >> 4) * 8 + (b & 7);
    return y < 196;
}

// ---------------------------------------------------------------------------
// Weights-resident MFMA GEMM (bf16 hi/lo A in memory).
//   C = Ah@Bh + Ah@Bl + Al@Bh (+bias); B^T [n][k] staged to LDS once;
//   barrier-free k-loop; A frags straight from global (16B/lane coalesced).
// Block: 512 threads = 8 waves; wave = 32 rows x (NJ*16) cols.
// ---------------------------------------------------------------------------
template<int NJ, int KSTEPS>
__global__ __launch_bounds__(512, 4) void gemm_wres(
    const ushort* __restrict__ Ah, const ushort* __restrict__ Al,
    const ushort* __restrict__ BTh, const ushort* __restrict__ BTl,
    const float* __restrict__ bias,
    ushort* __restrict__ Cb, int M, int lda, int ldc)
{
    constexpr int K  = KSTEPS * 32;
    constexpr int N  = NJ * 16;
    constexpr int KP = K + 8;                 // padded LDS stride (2-way alias = free)
    extern __shared__ ushort sB[];            // [2][N][KP]
    ushort* sBh = sB;
    ushort* sBl = sB + (size_t)N * KP;

    int bx, by;
    if (!swizzle400(blockIdx.x, bx, by)) return;

    const int tid     = threadIdx.x;
    const int colBase = bx * N;
    const ushort* Bh  = BTh + (size_t)colBase * K;
    const ushort* Bl  = BTl + (size_t)colBase * K;

    constexpr int KC8 = K / 8;
    for (int idx = tid; idx < N * KC8; idx += 512) {
        int n  = idx / KC8;
        int kc = idx % KC8;
        *(int4*)&sBh[n * KP + kc * 8] = *(const int4*)&Bh[(size_t)n * K + kc * 8];
        *(int4*)&sBl[n * KP + kc * 8] = *(const int4*)&Bl[(size_t)n * K + kc * 8];
    }
    __syncthreads();

    const int lane = tid & 63;
    const int wv   = tid >> 6;
    const int lm   = lane & 15, quad = lane >> 4;
    const int rowBase = by * 256 + wv * 32;

    f32x4 acc[2][NJ];
#pragma unroll
    for (int i = 0; i < 2; i++)
#pragma unroll
        for (int j = 0; j < NJ; j++)
#pragma unroll
            for (int t = 0; t < 4; t++) acc[i][j][t] = 0.f;

    for (int ks = 0; ks < KSTEPS; ks++) {
        const int ko = ks * 32 + quad * 8;
        bf16x8 ah[2], al[2];
#pragma unroll
        for (int i = 0; i < 2; i++) {
            int r = rowBase + i * 16 + lm;
            bool ok = r < M;
            size_t ao = (size_t)r * lda + ko;
            ah[i] = loadA8(&Ah[ao], ok);
            al[i] = loadA8(&Al[ao], ok);
        }
#pragma unroll
        for (int j = 0; j < NJ; j++) {
            int bo = (j * 16 + lm) * KP + ko;
            bf16x8 bh = *(const bf16x8*)&sBh[bo];
            bf16x8 bl = *(const bf16x8*)&sBl[bo];
            acc[0][j] = __builtin_amdgcn_mfma_f32_16x16x32_bf16(ah[0], bh, acc[0][j], 0, 0, 0);
            acc[1][j] = __builtin_amdgcn_mfma_f32_16x16x32_bf16(ah[1], bh, acc[1][j], 0, 0, 0);
            acc[0][j] = __builtin_amdgcn_mfma_f32_16x16x32_bf16(ah[0], bl, acc[0][j], 0, 0, 0);
            acc[1][j] = __builtin_amdgcn_mfma_f32_16x16x32_bf16(ah[1], bl, acc[1][j], 0, 0, 0);
            acc[0][j] = __builtin_amdgcn_mfma_f32_16x16x32_bf16(al[0], bh, acc[0][j], 0, 0, 0);
            acc[1][j] = __builtin_amdgcn_mfma_f32_16x16x32_bf16(al[1], bh, acc[1][j], 0, 0, 0);
        }
    }

    float bj[NJ];
#pragma unroll
    for (int j = 0; j < NJ; j++) bj[j] = bias ? bias[colBase + j * 16 + lm] : 0.f;

    // C/D layout: col = lane&15, row = quad*4 + reg
#pragma unroll
    for (int i = 0; i < 2; i++) {
#pragma unroll
        for (int t = 0; t < 4; t++) {
            int gr = rowBase + i * 16 + quad * 4 + t;
            if (gr < M) {
#pragma unroll
                for (int j = 0; j < NJ; j++) {
                    int gc = colBase + j * 16 + lm;
                    Cb[(size_t)gr * ldc + gc] = f2bf(acc[i][j][t] + bj[j]);
                }
            }
        }
    }
}

// ---------------------------------------------------------------------------
// In-projection GEMM: A is fp32 (h), hi/lo split done IN REGISTERS.
// Epilogue emits xh/xl exact hi/lo bf16 split.
// ---------------------------------------------------------------------------
template<int NJ, int KSTEPS>
__global__ __launch_bounds__(512, 4) void gemm_wres_f32(
    const float* __restrict__ A,
    const ushort* __restrict__ BTh, const ushort* __restrict__ BTl,
    const float* __restrict__ bias,
    ushort* __restrict__ Eh, ushort* __restrict__ El,
    int M, int lda, int ldc)
{
    constexpr int K  = KSTEPS * 32;
    constexpr int N  = NJ * 16;
    constexpr int KP = K + 8;
    extern __shared__ ushort sB[];
    ushort* sBh = sB;
    ushort* sBl = sB + (size_t)N * KP;

    int bx, by;
    if (!swizzle400(blockIdx.x, bx, by)) return;

    const int tid     = threadIdx.x;
    const int colBase = bx * N;
    const ushort* Bh  = BTh + (size_t)colBase * K;
    const ushort* Bl  = BTl + (size_t)colBase * K;

    constexpr int KC8 = K / 8;
    for (int idx = tid; idx < N * KC8; idx += 512) {
        int n  = idx / KC8;
        int kc = idx % KC8;
        *(int4*)&sBh[n * KP + kc * 8] = *(const int4*)&Bh[(size_t)n * K + kc * 8];
        *(int4*)&sBl[n * KP + kc * 8] = *(const int4*)&Bl[(size_t)n * K + kc * 8];
    }
    __syncthreads();

    const int lane = tid & 63;
    const int wv   = tid >> 6;
    const int lm   = lane & 15, quad = lane >> 4;
    const int rowBase = by * 256 + wv * 32;

    f32x4 acc[2][NJ];
#pragma unroll
    for (int i = 0; i < 2; i++)
#pragma unroll
        for (int j = 0; j < NJ; j++)
#pragma unroll
            for (int t = 0; t < 4; t++) acc[i][j][t] = 0.f;

    for (int ks = 0; ks < KSTEPS; ks++) {
        const int ko = ks * 32 + quad * 8;
        bf16x8 ah[2], al[2];
#pragma unroll
        for (int i = 0; i < 2; i++) {
            int r = rowBase + i * 16 + lm;
            float v[8];
            if (r < M) {
                const float* ap = &A[(size_t)r * lda + ko];
                *(float4*)&v[0] = *(const float4*)ap;
                *(float4*)&v[4] = *(const float4*)(ap + 4);
            } else {
#pragma unroll
                for (int q = 0; q < 8; q++) v[q] = 0.f;
            }
#pragma unroll
            for (int q = 0; q < 8; q++) {
                ushort hi = f2bf(v[q]);
                ah[i][q] = (short)hi;
                al[i][q] = (short)f2bf(v[q] - bf2f(hi));
            }
        }
#pragma unroll
        for (int j = 0; j < NJ; j++) {
            int bo = (j * 16 + lm) * KP + ko;
            bf16x8 bh = *(const bf16x8*)&sBh[bo];
            bf16x8 bl = *(const bf16x8*)&sBl[bo];
            acc[0][j] = __builtin_amdgcn_mfma_f32_16x16x32_bf16(ah[0], bh, acc[0][j], 0, 0, 0);
            acc[1][j] = __builtin_amdgcn_mfma_f32_16x16x32_bf16(ah[1], bh, acc[1][j], 0, 0, 0);
            acc[0][j] = __builtin_amdgcn_mfma_f32_16x16x32_bf16(ah[0], bl, acc[0][j], 0, 0, 0);
            acc[1][j] = __builtin_amdgcn_mfma_f32_16x16x32_bf16(ah[1], bl, acc[1][j], 0, 0, 0);
            acc[0][j] = __builtin_amdgcn_mfma_f32_16x16x32_bf16(al[0], bh, acc[0][j], 0, 0, 0);
            acc[1][j] = __builtin_amdgcn_mfma_f32_16x16x32_bf16(al[1], bh, acc[1][j], 0, 0, 0);
        }
    }

    float bj[NJ];
#pragma unroll
    for (int j = 0; j < NJ; j++) bj[j] = bias ? bias[colBase + j * 16 + lm] : 0.f;

#pragma unroll
    for (int i = 0; i < 2; i++) {
#pragma unroll
        for (int t = 0; t < 4; t++) {
            int gr = rowBase + i * 16 + quad * 4 + t;
            if (gr < M) {
#pragma unroll
                for (int j = 0; j < NJ; j++) {
                    int gc = colBase + j * 16 + lm;
                    float v = acc[i][j][t] + bj[j];
                    size_t ci = (size_t)gr * ldc + gc;
                    ushort hi = f2bf(v);
                    Eh[ci] = hi;
                    El[ci] = f2bf(v - bf2f(hi));
                }
            }
        }
    }
}

// ---------------------------------------------------------------------------
// weight prep
// ---------------------------------------------------------------------------
__global__ void conv_win(const float* __restrict__ W, ushort* __restrict__ Th,
                         ushort* __restrict__ Tl) {
    int id = blockIdx.x * 256 + threadIdx.x;            // 32768
    int k = id >> 7, n = id & 127;
    float v = W[id];
    ushort hi = f2bf(v);
    Th[n * 256 + k] = hi;
    Tl[n * 256 + k] = f2bf(v - bf2f(hi));
}

__global__ void conv_wzy(const float* __restrict__ Wm, const float* __restrict__ bm,
                         ushort* __restrict__ Th, ushort* __restrict__ Tl,
                         float* __restrict__ b256) {
    int id = blockIdx.x * 256 + threadIdx.x;            // 131072
    int l = id >> 15;
    int r = id & 32767;
    int n = r >> 7, k = r & 127;
    float v = (n < 128) ? Wm[l * 33280 + k * 128 + n]
                        : Wm[l * 33280 + (128 + k) * 128 + (n - 128)];
    ushort hi = f2bf(v);
    size_t o = (size_t)l * 32768 + (size_t)n * 128 + k;
    Th[o] = hi;
    Tl[o] = f2bf(v - bf2f(hi));
    if (k == 0) b256[l * 256 + n] = (n < 128) ? 0.f : bm[l * 128 + (n - 128)];
}

// ---------------------------------------------------------------------------
// CSR build
// ---------------------------------------------------------------------------
__global__ void hist_kernel(const int* __restrict__ dst, int* __restrict__ deg) {
    int e = blockIdx.x * 256 + threadIdx.x;
    if (e < NE) atomicAdd(&deg[dst[e]], 1);
}

__global__ void scan1_kernel(const int* __restrict__ deg, int* __restrict__ csr,
                             int* __restrict__ bsum) {
    __shared__ int s[256];
    int t = threadIdx.x;
    int n = blockIdx.x * 256 + t;
    int v = (n < NN) ? deg[n] : 0;
    s[t] = v; __syncthreads();
    for (int d = 1; d < 256; d <<= 1) {
        int u = (t >= d) ? s[t - d] : 0;
        __syncthreads();
        s[t] += u;
        __syncthreads();
    }
    if (n < NN) csr[n] = s[t] - v;
    if (t == 255) bsum[blockIdx.x] = s[t];
}

__global__ void scan2_kernel(const int* __restrict__ bsum, int* __restrict__ boff) {
    __shared__ int s[256];
    int t = threadIdx.x;
    int v = (t < 196) ? bsum[t] : 0;
    s[t] = v; __syncthreads();
    for (int d = 1; d < 256; d <<= 1) {
        int u = (t >= d) ? s[t - d] : 0;
        __syncthreads();
        s[t] += u;
        __syncthreads();
    }
    boff[t] = s[t] - v;
}

__global__ void scan3_kernel(int* __restrict__ csr, const int* __restrict__ boff) {
    int n = blockIdx.x * 256 + threadIdx.x;
    if (n < NN) csr[n] += boff[blockIdx.x];
    if (n == 0) csr[NN] = NE;
}

// fill: minimal scatter — only the 4B rank map eid[p]=e
__global__ void fill_kernel(const int* __restrict__ dst, const int* __restrict__ csr,
                            int* __restrict__ cursor, int* __restrict__ eid) {
    int e = blockIdx.x * 256 + threadIdx.x;
    if (e < NE) {
        int d = dst[e];
        int p = csr[d] + atomicAdd(&cursor[d], 1);
        eid[p] = e;
    }
}

// gather pass: coalesced writes of srcS/eaS in CSR order
__global__ void gather_kernel(const int* __restrict__ eid, const int* __restrict__ src,
                              const float* __restrict__ ea,
                              int* __restrict__ srcS, float* __restrict__ eaS) {
    int p = blockIdx.x * 256 + threadIdx.x;
    if (p < NE) {
        int e = eid[p];
        srcS[p] = src[e];
        *(float4*)&eaS[(size_t)p * 4] = *(const float4*)&ea[(size_t)e * 4];
    }
}

// ---------------------------------------------------------------------------
// Aggregation v3: 4 nodes per wave (16 lanes/node, 8 channels/lane).
// 4 independent gather streams/wave x 4-deep batches -> 4x memory parallelism.
// Last layer fuses the output projection (16-lane shfl reduction).
// ---------------------------------------------------------------------------
__global__ __launch_bounds__(256) void agg_kernel(
    const ushort* __restrict__ zy, const float* __restrict__ eaS,
    const float* __restrict__ W3,
    const int* __restrict__ srcS, const int* __restrict__ csr,
    ushort* __restrict__ xh, ushort* __restrict__ xl,
    const float* __restrict__ Wo, const float* __restrict__ bo,
    float* __restrict__ outp, int lastLayer)
{
    const int wv   = (blockIdx.x * 256 + threadIdx.x) >> 6;  // 0..12499
    const int lane = threadIdx.x & 63;
    const int g    = lane >> 4;          // node group 0..3
    const int li   = lane & 15;
    const int n    = wv * 4 + g;         // node id, exactly covers [0,50000)
    const int c0   = li * 8;             // channel base

    // W3 weights: w[d][q2] (d = edge-attr dim, q2 = channel pair)
    f32x2 w[4][4];
#pragma unroll
    for (int d = 0; d < 4; d++)
#pragma unroll
        for (int q2 = 0; q2 < 4; q2++) {
            float2 t = *(const float2*)&W3[d * HIDD + c0 + 2 * q2];
            w[d][q2] = {t.x, t.y};
        }

    // y (dst bias term) for this node's 8 channels
    uint4 yu = *(const uint4*)&zy[(size_t)n * 256 + 128 + c0];
    f32x2 y2[4] = {{lo16f(yu.x), hi16f(yu.x)}, {lo16f(yu.y), hi16f(yu.y)},
                   {lo16f(yu.z), hi16f(yu.z)}, {lo16f(yu.w), hi16f(yu.w)}};

    // state x = xh + xl (exact hi/lo pair)
    size_t xi = (size_t)n * HIDD + c0;
    uint4 uh = *(const uint4*)&xh[xi];
    uint4 ul = *(const uint4*)&xl[xi];
    f32x2 acc[4] = {{lo16f(uh.x) + lo16f(ul.x), hi16f(uh.x) + hi16f(ul.x)},
                    {lo16f(uh.y) + lo16f(ul.y), hi16f(uh.y) + hi16f(ul.y)},
                    {lo16f(uh.z) + lo16f(ul.z), hi16f(uh.z) + hi16f(ul.z)},
                    {lo16f(uh.w) + lo16f(ul.w), hi16f(uh.w) + hi16f(ul.w)}};

    int i = csr[n], end = csr[n + 1];

    for (; i + 4 <= end; i += 4) {
        int s0 = srcS[i], s1 = srcS[i + 1], s2 = srcS[i + 2], s3 = srcS[i + 3];
        uint4 z0 = *(const uint4*)&zy[(size_t)s0 * 256 + c0];
        uint4 z1 = *(const uint4*)&zy[(size_t)s1 * 256 + c0];
        uint4 z2 = *(const uint4*)&zy[(size_t)s2 * 256 + c0];
        uint4 z3 = *(const uint4*)&zy[(size_t)s3 * 256 + c0];
        float4 a0 = *(const float4*)&eaS[(size_t)(i + 0) * 4];
        float4 a1 = *(const float4*)&eaS[(size_t)(i + 1) * 4];
        float4 a2 = *(const float4*)&eaS[(size_t)(i + 2) * 4];
        float4 a3 = *(const float4*)&eaS[(size_t)(i + 3) * 4];
#pragma unroll
        for (int k = 0; k < 4; k++) {
            uint4  zk = (k == 0) ? z0 : (k == 1) ? z1 : (k == 2) ? z2 : z3;
            float4 ak = (k == 0) ? a0 : (k == 1) ? a1 : (k == 2) ? a2 : a3;
            const unsigned int zc[4] = {zk.x, zk.y, zk.z, zk.w};
#pragma unroll
            for (int q2 = 0; q2 < 4; q2++) {
                f32x2 m = {lo16f(zc[q2]), hi16f(zc[q2])};
                m += y2[q2];
                m += ak.x * w[0][q2];
                m += ak.y * w[1][q2];
                m += ak.z * w[2][q2];
                m += ak.w * w[3][q2];
                acc[q2].x += fmaxf(m.x, 0.f);
                acc[q2].y += fmaxf(m.y, 0.f);
            }
        }
    }
    for (; i < end; i++) {
        int sx = srcS[i];
        uint4 zk = *(const uint4*)&zy[(size_t)sx * 256 + c0];
        float4 ak = *(const float4*)&eaS[(size_t)i * 4];
        const unsigned int zc[4] = {zk.x, zk.y, zk.z, zk.w};
#pragma unroll
        for (int q2 = 0; q2 < 4; q2++) {
            f32x2 m = {lo16f(zc[q2]), hi16f(zc[q2])};
            m += y2[q2];
            m += ak.x * w[0][q2];
            m += ak.y * w[1][q2];
            m += ak.z * w[2][q2];
            m += ak.w * w[3][q2];
            acc[q2].x += fmaxf(m.x, 0.f);
            acc[q2].y += fmaxf(m.y, 0.f);
        }
    }

    if (!lastLayer) {
        uint4 oh, ol;
        unsigned int* ph = &oh.x;
        unsigned int* pl = &ol.x;
#pragma unroll
        for (int q2 = 0; q2 < 4; q2++) {
            ushort h0 = f2bf(acc[q2].x), h1 = f2bf(acc[q2].y);
            ushort l0 = f2bf(acc[q2].x - bf2f(h0)), l1 = f2bf(acc[q2].y - bf2f(h1));
            ph[q2] = (unsigned int)h0 | ((unsigned int)h1 << 16);
            pl[q2] = (unsigned int)l0 | ((unsigned int)l1 << 16);
        }
        *(uint4*)&xh[xi] = oh;
        *(uint4*)&xl[xi] = ol;
    } else {
        // fused output projection: out[n] = x[n] @ W_out + b_out
        float p0 = 0.f, p1 = 0.f, p2 = 0.f;
#pragma unroll
        for (int q = 0; q < 8; q++) {
            float xv = (q & 1) ? acc[q >> 1].y : acc[q >> 1].x;
            int ch = c0 + q;
            p0 += xv * Wo[ch * ODIM + 0];
            p1 += xv * Wo[ch * ODIM + 1];
            p2 += xv * Wo[ch * ODIM + 2];
        }
#pragma unroll
        for (int off = 1; off < 16; off <<= 1) {
            p0 += __shfl_xor(p0, off);
            p1 += __shfl_xor(p1, off);
            p2 += __shfl_xor(p2, off);
        }
        if (li == 0) {
            outp[(size_t)n * ODIM + 0] = p0 + bo[0];
            outp[(size_t)n * ODIM + 1] = p1 + bo[1];
            outp[(size_t)n * ODIM + 2] = p2 + bo[2];
        }
    }
}

// ---------------------------------------------------------------------------
extern "C" void kernel_launch(void* const* d_in, const int* in_sizes, int n_in,
                              void* d_out, int out_size, void* d_ws, size_t ws_size,
                              hipStream_t stream)
{
    const float* h     = (const float*)d_in[0];
    const int*   ei    = (const int*)  d_in[1];
    const float* ea    = (const float*)d_in[2];
    const float* W_in  = (const float*)d_in[3];
    const float* b_in  = (const float*)d_in[4];
    const float* W_msg = (const float*)d_in[5];
    const float* b_msg = (const float*)d_in[6];
    const float* W_out = (const float*)d_in[7];
    const float* b_out = (const float*)d_in[8];
    float* out = (float*)d_out;

    // workspace carve-up (~78 MB)
    ushort* zy     = (ushort*)d_ws;                        // 12.8M us
    float*  eaS    = (float*)(zy + 12800000);              // 3.2M f
    int*    srcS   = (int*)(eaS + 3200000);                // 800k
    int*    eidArr = srcS + 800000;                        // 800k
    int*    deg    = eidArr + 800000;                      // 50176
    int*    cursor = deg + 50176;                          // 50176
    int*    csr    = cursor + 50176;                       // NN+1 used
    int*    bsum   = csr + 50176;                          // 256
    int*    boff   = bsum + 256;                           // 256
    ushort* xh     = (ushort*)(boff + 256);                // 6.4M us
    ushort* xl     = xh + 6400000;                         // 6.4M us
    ushort* winTh  = xl + 6400000;                         // 32768
    ushort* winTl  = winTh + 32768;                        // 32768
    ushort* wzyTh  = winTl + 32768;                        // 131072
    ushort* wzyTl  = wzyTh + 131072;                       // 131072
    float*  bias256= (float*)(wzyTl + 131072);             // 1024 f

    const int* srcA = ei;        // edge_index[0]
    const int* dstA = ei + NE;   // edge_index[1]

    // allow >64KB dynamic LDS
    hipFuncSetAttribute((const void*)&gemm_wres<8, 4>,
                        hipFuncAttributeMaxDynamicSharedMemorySize, 2 * 128 * 136 * 2);
    hipFuncSetAttribute((const void*)&gemm_wres_f32<4, 8>,
                        hipFuncAttributeMaxDynamicSharedMemorySize, 2 * 64 * 264 * 2);

    // weight prep (tiny)
    conv_win<<<128, 256, 0, stream>>>(W_in, winTh, winTl);
    conv_wzy<<<512, 256, 0, stream>>>(W_msg, b_msg, wzyTh, wzyTl, bias256);

    // CSR build: zero deg+cursor (adjacent) via memset, rank map, gather
    hipMemsetAsync(deg, 0, 2 * 50176 * sizeof(int), stream);
    hist_kernel <<<3125, 256, 0, stream>>>(dstA, deg);
    scan1_kernel<<<196, 256, 0, stream>>>(deg, csr, bsum);
    scan2_kernel<<<1, 256, 0, stream>>>(bsum, boff);
    scan3_kernel<<<196, 256, 0, stream>>>(csr, boff);
    fill_kernel <<<3125, 256, 0, stream>>>(dstA, csr, cursor, eidArr);
    gather_kernel<<<3125, 256, 0, stream>>>(eidArr, srcA, ea, srcS, eaS);

    // input projection straight from fp32 h (in-register hi/lo split)
    gemm_wres_f32<4, 8><<<400, 512, 2 * 64 * 264 * 2, stream>>>(
        h, winTh, winTl, b_in, xh, xl, NN, INDIM, HIDD);

    for (int l = 0; l < NLAYERS; l++) {
        gemm_wres<8, 4><<<400, 512, 2 * 128 * 136 * 2, stream>>>(
            xh, xl, wzyTh + (size_t)l * 32768, wzyTl + (size_t)l * 32768,
            bias256 + l * 256, zy, NN, HIDD, 256);
        agg_kernel<<<3125, 256, 0, stream>>>(
            zy, eaS, W_msg + (size_t)l * 33280 + 256 * 128,
            srcS, csr, xh, xl, W_out, b_out, out,
            (l == NLAYERS - 1) ? 1 : 0);
    }
}

// Round 8
// 462.506 us; speedup vs baseline: 2.3025x; 1.0468x over previous
//
#include <hip/hip_runtime.h>

#define NN 50000
#define NE 800000
#define INDIM 256
#define HIDD 128
#define ODIM 3
#define EDIM 4
#define NLAYERS 4

typedef __attribute__((ext_vector_type(8))) short bf16x8;
typedef __attribute__((ext_vector_type(4))) float f32x4;
typedef __attribute__((ext_vector_type(2))) float f32x2;

// round-to-nearest-even fp32 -> bf16 bits (finite inputs)
__device__ __forceinline__ ushort f2bf(float f) {
    unsigned int x = __float_as_uint(f);
    unsigned int r = (x + 0x7fffu + ((x >> 16) & 1u)) >> 16;
    return (ushort)r;
}
__device__ __forceinline__ float bf2f(ushort u) {
    return __uint_as_float(((unsigned int)u) << 16);
}
__device__ __forceinline__ float lo16f(unsigned int u) {
    return __uint_as_float(u << 16);
}
__device__ __forceinline__ float hi16f(unsigned int u) {
    return __uint_as_float(u & 0xffff0000u);
}

__device__ __forceinline__ bf16x8 loadA8(const ushort* p, bool ok) {
    if (ok) return *(const bf16x8*)p;
    bf16x8 z = {0, 0, 0, 0, 0, 0, 0, 0};
    return z;
}

// XCD-pairing swizzle: 1D grid of 400; col-half pair (x=0/1, same y) differs
// by 8 in block id -> same XCD under round-robin assignment (perf-only hint).
__device__ __forceinline__ bool swizzle400(int b, int& x, int& y) {
    x = (b >> 3) & 1;
    y = (b >> 4) * 8 + (b & 7);
    return y < 196;
}

// ---------------------------------------------------------------------------
// Weights-resident MFMA GEMM (bf16 hi/lo A in memory).
//   C = Ah@Bh + Ah@Bl + Al@Bh (+bias); B^T [n][k] staged to LDS once;
//   barrier-free k-loop; A frags straight from global (16B/lane coalesced).
// ---------------------------------------------------------------------------
template<int NJ, int KSTEPS>
__global__ __launch_bounds__(512, 4) void gemm_wres(
    const ushort* __restrict__ Ah, const ushort* __restrict__ Al,
    const ushort* __restrict__ BTh, const ushort* __restrict__ BTl,
    const float* __restrict__ bias,
    ushort* __restrict__ Cb, int M, int lda, int ldc)
{
    constexpr int K  = KSTEPS * 32;
    constexpr int N  = NJ * 16;
    constexpr int KP = K + 8;                 // padded LDS stride (2-way alias = free)
    extern __shared__ ushort sB[];            // [2][N][KP]
    ushort* sBh = sB;
    ushort* sBl = sB + (size_t)N * KP;

    int bx, by;
    if (!swizzle400(blockIdx.x, bx, by)) return;

    const int tid     = threadIdx.x;
    const int colBase = bx * N;
    const ushort* Bh  = BTh + (size_t)colBase * K;
    const ushort* Bl  = BTl + (size_t)colBase * K;

    constexpr int KC8 = K / 8;
    for (int idx = tid; idx < N * KC8; idx += 512) {
        int n  = idx / KC8;
        int kc = idx % KC8;
        *(int4*)&sBh[n * KP + kc * 8] = *(const int4*)&Bh[(size_t)n * K + kc * 8];
        *(int4*)&sBl[n * KP + kc * 8] = *(const int4*)&Bl[(size_t)n * K + kc * 8];
    }
    __syncthreads();

    const int lane = tid & 63;
    const int wv   = tid >> 6;
    const int lm   = lane & 15, quad = lane >> 4;
    const int rowBase = by * 256 + wv * 32;

    f32x4 acc[2][NJ];
#pragma unroll
    for (int i = 0; i < 2; i++)
#pragma unroll
        for (int j = 0; j < NJ; j++)
#pragma unroll
            for (int t = 0; t < 4; t++) acc[i][j][t] = 0.f;

    for (int ks = 0; ks < KSTEPS; ks++) {
        const int ko = ks * 32 + quad * 8;
        bf16x8 ah[2], al[2];
#pragma unroll
        for (int i = 0; i < 2; i++) {
            int r = rowBase + i * 16 + lm;
            bool ok = r < M;
            size_t ao = (size_t)r * lda + ko;
            ah[i] = loadA8(&Ah[ao], ok);
            al[i] = loadA8(&Al[ao], ok);
        }
#pragma unroll
        for (int j = 0; j < NJ; j++) {
            int bo = (j * 16 + lm) * KP + ko;
            bf16x8 bh = *(const bf16x8*)&sBh[bo];
            bf16x8 bl = *(const bf16x8*)&sBl[bo];
            acc[0][j] = __builtin_amdgcn_mfma_f32_16x16x32_bf16(ah[0], bh, acc[0][j], 0, 0, 0);
            acc[1][j] = __builtin_amdgcn_mfma_f32_16x16x32_bf16(ah[1], bh, acc[1][j], 0, 0, 0);
            acc[0][j] = __builtin_amdgcn_mfma_f32_16x16x32_bf16(ah[0], bl, acc[0][j], 0, 0, 0);
            acc[1][j] = __builtin_amdgcn_mfma_f32_16x16x32_bf16(ah[1], bl, acc[1][j], 0, 0, 0);
            acc[0][j] = __builtin_amdgcn_mfma_f32_16x16x32_bf16(al[0], bh, acc[0][j], 0, 0, 0);
            acc[1][j] = __builtin_amdgcn_mfma_f32_16x16x32_bf16(al[1], bh, acc[1][j], 0, 0, 0);
        }
    }

    float bj[NJ];
#pragma unroll
    for (int j = 0; j < NJ; j++) bj[j] = bias ? bias[colBase + j * 16 + lm] : 0.f;

    // C/D layout: col = lane&15, row = quad*4 + reg
#pragma unroll
    for (int i = 0; i < 2; i++) {
#pragma unroll
        for (int t = 0; t < 4; t++) {
            int gr = rowBase + i * 16 + quad * 4 + t;
            if (gr < M) {
#pragma unroll
                for (int j = 0; j < NJ; j++) {
                    int gc = colBase + j * 16 + lm;
                    Cb[(size_t)gr * ldc + gc] = f2bf(acc[i][j][t] + bj[j]);
                }
            }
        }
    }
}

// ---------------------------------------------------------------------------
// In-projection GEMM: A is fp32 (h), hi/lo split done IN REGISTERS.
// Epilogue emits xh/xl exact hi/lo bf16 split.
// ---------------------------------------------------------------------------
template<int NJ, int KSTEPS>
__global__ __launch_bounds__(512, 4) void gemm_wres_f32(
    const float* __restrict__ A,
    const ushort* __restrict__ BTh, const ushort* __restrict__ BTl,
    const float* __restrict__ bias,
    ushort* __restrict__ Eh, ushort* __restrict__ El,
    int M, int lda, int ldc)
{
    constexpr int K  = KSTEPS * 32;
    constexpr int N  = NJ * 16;
    constexpr int KP = K + 8;
    extern __shared__ ushort sB[];
    ushort* sBh = sB;
    ushort* sBl = sB + (size_t)N * KP;

    int bx, by;
    if (!swizzle400(blockIdx.x, bx, by)) return;

    const int tid     = threadIdx.x;
    const int colBase = bx * N;
    const ushort* Bh  = BTh + (size_t)colBase * K;
    const ushort* Bl  = BTl + (size_t)colBase * K;

    constexpr int KC8 = K / 8;
    for (int idx = tid; idx < N * KC8; idx += 512) {
        int n  = idx / KC8;
        int kc = idx % KC8;
        *(int4*)&sBh[n * KP + kc * 8] = *(const int4*)&Bh[(size_t)n * K + kc * 8];
        *(int4*)&sBl[n * KP + kc * 8] = *(const int4*)&Bl[(size_t)n * K + kc * 8];
    }
    __syncthreads();

    const int lane = tid & 63;
    const int wv   = tid >> 6;
    const int lm   = lane & 15, quad = lane >> 4;
    const int rowBase = by * 256 + wv * 32;

    f32x4 acc[2][NJ];
#pragma unroll
    for (int i = 0; i < 2; i++)
#pragma unroll
        for (int j = 0; j < NJ; j++)
#pragma unroll
            for (int t = 0; t < 4; t++) acc[i][j][t] = 0.f;

    for (int ks = 0; ks < KSTEPS; ks++) {
        const int ko = ks * 32 + quad * 8;
        bf16x8 ah[2], al[2];
#pragma unroll
        for (int i = 0; i < 2; i++) {
            int r = rowBase + i * 16 + lm;
            float v[8];
            if (r < M) {
                const float* ap = &A[(size_t)r * lda + ko];
                *(float4*)&v[0] = *(const float4*)ap;
                *(float4*)&v[4] = *(const float4*)(ap + 4);
            } else {
#pragma unroll
                for (int q = 0; q < 8; q++) v[q] = 0.f;
            }
#pragma unroll
            for (int q = 0; q < 8; q++) {
                ushort hi = f2bf(v[q]);
                ah[i][q] = (short)hi;
                al[i][q] = (short)f2bf(v[q] - bf2f(hi));
            }
        }
#pragma unroll
        for (int j = 0; j < NJ; j++) {
            int bo = (j * 16 + lm) * KP + ko;
            bf16x8 bh = *(const bf16x8*)&sBh[bo];
            bf16x8 bl = *(const bf16x8*)&sBl[bo];
            acc[0][j] = __builtin_amdgcn_mfma_f32_16x16x32_bf16(ah[0], bh, acc[0][j], 0, 0, 0);
            acc[1][j] = __builtin_amdgcn_mfma_f32_16x16x32_bf16(ah[1], bh, acc[1][j], 0, 0, 0);
            acc[0][j] = __builtin_amdgcn_mfma_f32_16x16x32_bf16(ah[0], bl, acc[0][j], 0, 0, 0);
            acc[1][j] = __builtin_amdgcn_mfma_f32_16x16x32_bf16(ah[1], bl, acc[1][j], 0, 0, 0);
            acc[0][j] = __builtin_amdgcn_mfma_f32_16x16x32_bf16(al[0], bh, acc[0][j], 0, 0, 0);
            acc[1][j] = __builtin_amdgcn_mfma_f32_16x16x32_bf16(al[1], bh, acc[1][j], 0, 0, 0);
        }
    }

    float bj[NJ];
#pragma unroll
    for (int j = 0; j < NJ; j++) bj[j] = bias ? bias[colBase + j * 16 + lm] : 0.f;

#pragma unroll
    for (int i = 0; i < 2; i++) {
#pragma unroll
        for (int t = 0; t < 4; t++) {
            int gr = rowBase + i * 16 + quad * 4 + t;
            if (gr < M) {
#pragma unroll
                for (int j = 0; j < NJ; j++) {
                    int gc = colBase + j * 16 + lm;
                    float v = acc[i][j][t] + bj[j];
                    size_t ci = (size_t)gr * ldc + gc;
                    ushort hi = f2bf(v);
                    Eh[ci] = hi;
                    El[ci] = f2bf(v - bf2f(hi));
                }
            }
        }
    }
}

// ---------------------------------------------------------------------------
// merged weight prep: ids [0,32768) -> W_in transpose+split,
//                     ids [32768, 32768+131072) -> W_msg fused [W1|W2] + bias
// ---------------------------------------------------------------------------
__global__ void conv_weights(const float* __restrict__ Win, const float* __restrict__ Wm,
                             const float* __restrict__ bm,
                             ushort* __restrict__ winTh, ushort* __restrict__ winTl,
                             ushort* __restrict__ wzyTh, ushort* __restrict__ wzyTl,
                             float* __restrict__ b256) {
    int id = blockIdx.x * 256 + threadIdx.x;
    if (id < 32768) {
        int k = id >> 7, n = id & 127;
        float v = Win[id];
        ushort hi = f2bf(v);
        winTh[n * 256 + k] = hi;
        winTl[n * 256 + k] = f2bf(v - bf2f(hi));
    } else {
        int id2 = id - 32768;                  // 0..131071
        int l = id2 >> 15;
        int r = id2 & 32767;
        int n = r >> 7, k = r & 127;
        float v = (n < 128) ? Wm[l * 33280 + k * 128 + n]
                            : Wm[l * 33280 + (128 + k) * 128 + (n - 128)];
        ushort hi = f2bf(v);
        size_t o = (size_t)l * 32768 + (size_t)n * 128 + k;
        wzyTh[o] = hi;
        wzyTl[o] = f2bf(v - bf2f(hi));
        if (k == 0) b256[l * 256 + n] = (n < 128) ? 0.f : bm[l * 128 + (n - 128)];
    }
}

// ---------------------------------------------------------------------------
// CSR build: one atomic pass (deg+rank), scan, atomic-free scatter, gather
// ---------------------------------------------------------------------------
__global__ void histrank_kernel(const int* __restrict__ dst, int* __restrict__ deg,
                                int* __restrict__ rank) {
    int e = blockIdx.x * 256 + threadIdx.x;
    if (e < NE) rank[e] = atomicAdd(&deg[dst[e]], 1);
}

__global__ void scan1_kernel(const int* __restrict__ deg, int* __restrict__ csr,
                             int* __restrict__ bsum) {
    __shared__ int s[256];
    int t = threadIdx.x;
    int n = blockIdx.x * 256 + t;
    int v = (n < NN) ? deg[n] : 0;
    s[t] = v; __syncthreads();
    for (int d = 1; d < 256; d <<= 1) {
        int u = (t >= d) ? s[t - d] : 0;
        __syncthreads();
        s[t] += u;
        __syncthreads();
    }
    if (n < NN) csr[n] = s[t] - v;
    if (t == 255) bsum[blockIdx.x] = s[t];
}

__global__ void scan2_kernel(const int* __restrict__ bsum, int* __restrict__ boff) {
    __shared__ int s[256];
    int t = threadIdx.x;
    int v = (t < 196) ? bsum[t] : 0;
    s[t] = v; __syncthreads();
    for (int d = 1; d < 256; d <<= 1) {
        int u = (t >= d) ? s[t - d] : 0;
        __syncthreads();
        s[t] += u;
        __syncthreads();
    }
    boff[t] = s[t] - v;
}

__global__ void scan3_kernel(int* __restrict__ csr, const int* __restrict__ boff) {
    int n = blockIdx.x * 256 + threadIdx.x;
    if (n < NN) csr[n] += boff[blockIdx.x];
    if (n == 0) csr[NN] = NE;
}

// atomic-free scatter of the 4B rank map
__global__ void scatter_kernel(const int* __restrict__ dst, const int* __restrict__ rank,
                               const int* __restrict__ csr, int* __restrict__ eid) {
    int e = blockIdx.x * 256 + threadIdx.x;
    if (e < NE) eid[csr[dst[e]] + rank[e]] = e;
}

// coalesced gather of srcS/eaS in CSR order
__global__ void gather_kernel(const int* __restrict__ eid, const int* __restrict__ src,
                              const float* __restrict__ ea,
                              int* __restrict__ srcS, float* __restrict__ eaS) {
    int p = blockIdx.x * 256 + threadIdx.x;
    if (p < NE) {
        int e = eid[p];
        srcS[p] = src[e];
        *(float4*)&eaS[(size_t)p * 4] = *(const float4*)&ea[(size_t)e * 4];
    }
}

// ---------------------------------------------------------------------------
// Aggregation v4: 4 nodes per wave (16 lanes/node, 8 channels/lane),
// 8-deep edge batches -> up to 32 outstanding gathers/wave.
// __launch_bounds__(256,3): VGPR cap ~170 so the batch stays register-resident.
// Last layer fuses the output projection (16-lane shfl reduction).
// ---------------------------------------------------------------------------
__global__ __launch_bounds__(256, 3) void agg_kernel(
    const ushort* __restrict__ zy, const float* __restrict__ eaS,
    const float* __restrict__ W3,
    const int* __restrict__ srcS, const int* __restrict__ csr,
    ushort* __restrict__ xh, ushort* __restrict__ xl,
    const float* __restrict__ Wo, const float* __restrict__ bo,
    float* __restrict__ outp, int lastLayer)
{
    const int wv   = (blockIdx.x * 256 + threadIdx.x) >> 6;  // 0..12499
    const int lane = threadIdx.x & 63;
    const int g    = lane >> 4;          // node group 0..3
    const int li   = lane & 15;
    const int n    = wv * 4 + g;         // node id, exactly covers [0,50000)
    const int c0   = li * 8;             // channel base

    f32x2 w[4][4];
#pragma unroll
    for (int d = 0; d < 4; d++)
#pragma unroll
        for (int q2 = 0; q2 < 4; q2++) {
            float2 t = *(const float2*)&W3[d * HIDD + c0 + 2 * q2];
            w[d][q2] = {t.x, t.y};
        }

    uint4 yu = *(const uint4*)&zy[(size_t)n * 256 + 128 + c0];
    f32x2 y2[4] = {{lo16f(yu.x), hi16f(yu.x)}, {lo16f(yu.y), hi16f(yu.y)},
                   {lo16f(yu.z), hi16f(yu.z)}, {lo16f(yu.w), hi16f(yu.w)}};

    size_t xi = (size_t)n * HIDD + c0;
    uint4 uh = *(const uint4*)&xh[xi];
    uint4 ul = *(const uint4*)&xl[xi];
    f32x2 acc[4] = {{lo16f(uh.x) + lo16f(ul.x), hi16f(uh.x) + hi16f(ul.x)},
                    {lo16f(uh.y) + lo16f(ul.y), hi16f(uh.y) + hi16f(ul.y)},
                    {lo16f(uh.z) + lo16f(ul.z), hi16f(uh.z) + hi16f(ul.z)},
                    {lo16f(uh.w) + lo16f(ul.w), hi16f(uh.w) + hi16f(ul.w)}};

    int i = csr[n], end = csr[n + 1];

    // 8-deep batches
    for (; i + 8 <= end; i += 8) {
        int s[8];
#pragma unroll
        for (int k = 0; k < 8; k++) s[k] = srcS[i + k];
        uint4 z[8];
#pragma unroll
        for (int k = 0; k < 8; k++)
            z[k] = *(const uint4*)&zy[(size_t)s[k] * 256 + c0];
        float4 a[8];
#pragma unroll
        for (int k = 0; k < 8; k++)
            a[k] = *(const float4*)&eaS[(size_t)(i + k) * 4];
#pragma unroll
        for (int k = 0; k < 8; k++) {
            const unsigned int zc[4] = {z[k].x, z[k].y, z[k].z, z[k].w};
#pragma unroll
            for (int q2 = 0; q2 < 4; q2++) {
                f32x2 m = {lo16f(zc[q2]), hi16f(zc[q2])};
                m += y2[q2];
                m += a[k].x * w[0][q2];
                m += a[k].y * w[1][q2];
                m += a[k].z * w[2][q2];
                m += a[k].w * w[3][q2];
                acc[q2].x += fmaxf(m.x, 0.f);
                acc[q2].y += fmaxf(m.y, 0.f);
            }
        }
    }
    // 4-deep
    for (; i + 4 <= end; i += 4) {
        int s[4];
#pragma unroll
        for (int k = 0; k < 4; k++) s[k] = srcS[i + k];
        uint4 z[4];
#pragma unroll
        for (int k = 0; k < 4; k++)
            z[k] = *(const uint4*)&zy[(size_t)s[k] * 256 + c0];
        float4 a[4];
#pragma unroll
        for (int k = 0; k < 4; k++)
            a[k] = *(const float4*)&eaS[(size_t)(i + k) * 4];
#pragma unroll
        for (int k = 0; k < 4; k++) {
            const unsigned int zc[4] = {z[k].x, z[k].y, z[k].z, z[k].w};
#pragma unroll
            for (int q2 = 0; q2 < 4; q2++) {
                f32x2 m = {lo16f(zc[q2]), hi16f(zc[q2])};
                m += y2[q2];
                m += a[k].x * w[0][q2];
                m += a[k].y * w[1][q2];
                m += a[k].z * w[2][q2];
                m += a[k].w * w[3][q2];
                acc[q2].x += fmaxf(m.x, 0.f);
                acc[q2].y += fmaxf(m.y, 0.f);
            }
        }
    }
    // scalar tail
    for (; i < end; i++) {
        int sx = srcS[i];
        uint4 zk = *(const uint4*)&zy[(size_t)sx * 256 + c0];
        float4 ak = *(const float4*)&eaS[(size_t)i * 4];
        const unsigned int zc[4] = {zk.x, zk.y, zk.z, zk.w};
#pragma unroll
        for (int q2 = 0; q2 < 4; q2++) {
            f32x2 m = {lo16f(zc[q2]), hi16f(zc[q2])};
            m += y2[q2];
            m += ak.x * w[0][q2];
            m += ak.y * w[1][q2];
            m += ak.z * w[2][q2];
            m += ak.w * w[3][q2];
            acc[q2].x += fmaxf(m.x, 0.f);
            acc[q2].y += fmaxf(m.y, 0.f);
        }
    }

    if (!lastLayer) {
        uint4 oh, ol;
        unsigned int* ph = &oh.x;
        unsigned int* pl = &ol.x;
#pragma unroll
        for (int q2 = 0; q2 < 4; q2++) {
            ushort h0 = f2bf(acc[q2].x), h1 = f2bf(acc[q2].y);
            ushort l0 = f2bf(acc[q2].x - bf2f(h0)), l1 = f2bf(acc[q2].y - bf2f(h1));
            ph[q2] = (unsigned int)h0 | ((unsigned int)h1 << 16);
            pl[q2] = (unsigned int)l0 | ((unsigned int)l1 << 16);
        }
        *(uint4*)&xh[xi] = oh;
        *(uint4*)&xl[xi] = ol;
    } else {
        float p0 = 0.f, p1 = 0.f, p2 = 0.f;
#pragma unroll
        for (int q = 0; q < 8; q++) {
            float xv = (q & 1) ? acc[q >> 1].y : acc[q >> 1].x;
            int ch = c0 + q;
            p0 += xv * Wo[ch * ODIM + 0];
            p1 += xv * Wo[ch * ODIM + 1];
            p2 += xv * Wo[ch * ODIM + 2];
        }
#pragma unroll
        for (int off = 1; off < 16; off <<= 1) {
            p0 += __shfl_xor(p0, off);
            p1 += __shfl_xor(p1, off);
            p2 += __shfl_xor(p2, off);
        }
        if (li == 0) {
            outp[(size_t)n * ODIM + 0] = p0 + bo[0];
            outp[(size_t)n * ODIM + 1] = p1 + bo[1];
            outp[(size_t)n * ODIM + 2] = p2 + bo[2];
        }
    }
}

// ---------------------------------------------------------------------------
extern "C" void kernel_launch(void* const* d_in, const int* in_sizes, int n_in,
                              void* d_out, int out_size, void* d_ws, size_t ws_size,
                              hipStream_t stream)
{
    const float* h     = (const float*)d_in[0];
    const int*   ei    = (const int*)  d_in[1];
    const float* ea    = (const float*)d_in[2];
    const float* W_in  = (const float*)d_in[3];
    const float* b_in  = (const float*)d_in[4];
    const float* W_msg = (const float*)d_in[5];
    const float* b_msg = (const float*)d_in[6];
    const float* W_out = (const float*)d_in[7];
    const float* b_out = (const float*)d_in[8];
    float* out = (float*)d_out;

    // workspace carve-up (~81 MB)
    ushort* zy     = (ushort*)d_ws;                        // 12.8M us
    float*  eaS    = (float*)(zy + 12800000);              // 3.2M f
    int*    srcS   = (int*)(eaS + 3200000);                // 800k
    int*    eidArr = srcS + 800000;                        // 800k
    int*    rank   = eidArr + 800000;                      // 800k
    int*    deg    = rank + 800000;                        // 50176
    int*    csr    = deg + 50176;                          // NN+1 used
    int*    bsum   = csr + 50176;                          // 256
    int*    boff   = bsum + 256;                           // 256
    ushort* xh     = (ushort*)(boff + 256);                // 6.4M us
    ushort* xl     = xh + 6400000;                         // 6.4M us
    ushort* winTh  = xl + 6400000;                         // 32768
    ushort* winTl  = winTh + 32768;                        // 32768
    ushort* wzyTh  = winTl + 32768;                        // 131072
    ushort* wzyTl  = wzyTh + 131072;                       // 131072
    float*  bias256= (float*)(wzyTl + 131072);             // 1024 f

    const int* srcA = ei;        // edge_index[0]
    const int* dstA = ei + NE;   // edge_index[1]

    // allow >64KB dynamic LDS
    hipFuncSetAttribute((const void*)&gemm_wres<8, 4>,
                        hipFuncAttributeMaxDynamicSharedMemorySize, 2 * 128 * 136 * 2);
    hipFuncSetAttribute((const void*)&gemm_wres_f32<4, 8>,
                        hipFuncAttributeMaxDynamicSharedMemorySize, 2 * 64 * 264 * 2);

    // weight prep (merged)
    conv_weights<<<640, 256, 0, stream>>>(W_in, W_msg, b_msg,
                                          winTh, winTl, wzyTh, wzyTl, bias256);

    // CSR build
    hipMemsetAsync(deg, 0, 50176 * sizeof(int), stream);
    histrank_kernel<<<3125, 256, 0, stream>>>(dstA, deg, rank);
    scan1_kernel<<<196, 256, 0, stream>>>(deg, csr, bsum);
    scan2_kernel<<<1, 256, 0, stream>>>(bsum, boff);
    scan3_kernel<<<196, 256, 0, stream>>>(csr, boff);
    scatter_kernel<<<3125, 256, 0, stream>>>(dstA, rank, csr, eidArr);
    gather_kernel<<<3125, 256, 0, stream>>>(eidArr, srcA, ea, srcS, eaS);

    // input projection straight from fp32 h (in-register hi/lo split)
    gemm_wres_f32<4, 8><<<400, 512, 2 * 64 * 264 * 2, stream>>>(
        h, winTh, winTl, b_in, xh, xl, NN, INDIM, HIDD);

    for (int l = 0; l < NLAYERS; l++) {
        gemm_wres<8, 4><<<400, 512, 2 * 128 * 136 * 2, stream>>>(
            xh, xl, wzyTh + (size_t)l * 32768, wzyTl + (size_t)l * 32768,
            bias256 + l * 256, zy, NN, HIDD, 256);
        agg_kernel<<<3125, 256, 0, stream>>>(
            zy, eaS, W_msg + (size_t)l * 33280 + 256 * 128,
            srcS, csr, xh, xl, W_out, b_out, out,
            (l == NLAYERS - 1) ? 1 : 0);
    }
}